// Round 16
// baseline (262.346 us; speedup 1.0000x reference)
//
#include <hip/hip_runtime.h>
#include <hip/hip_bf16.h>

#define NN 50000
#define NE 500000
#define F 128
#define K_IN 128
#define ED 64
#define C 2
#define NEG 0.2f
#define FLTMAX 3.402823466e38f
#define PROJ_BLOCKS 782
#define HIST_BLOCKS 1954

typedef __attribute__((ext_vector_type(8))) short short8;
typedef __attribute__((ext_vector_type(8))) unsigned short ushort8;
typedef __attribute__((ext_vector_type(4))) float f32x4;

__device__ __forceinline__ short bf16r(float f) {
    unsigned u = __float_as_uint(f);
    unsigned r = (u + 0x7fffu + ((u >> 16) & 1u)) >> 16;
    return (short)r;
}

__device__ __forceinline__ float b2f(unsigned short v) {
    return __uint_as_float(((unsigned)v) << 16);
}

__device__ __forceinline__ short8 ldfrag(const float* base) {
    const float4* p = reinterpret_cast<const float4*>(base);
    float4 v0 = p[0], v1 = p[1];
    short8 r;
    r[0] = bf16r(v0.x); r[1] = bf16r(v0.y); r[2] = bf16r(v0.z); r[3] = bf16r(v0.w);
    r[4] = bf16r(v1.x); r[5] = bf16r(v1.y); r[6] = bf16r(v1.z); r[7] = bf16r(v1.w);
    return r;
}

// packed xb layout: xbp[n*128 + col*8 + t] = bf16(x_base[n][t*16+col])
// ---------------- fused: proj (blocks < PROJ_BLOCKS) + hist (rest) ----------------
__global__ __launch_bounds__(256) void proj_hist(const float* __restrict__ x,
                                                 const float* __restrict__ W_l,
                                                 unsigned short* __restrict__ xbp,
                                                 const int* __restrict__ ei,
                                                 int* __restrict__ counts) {
    if (blockIdx.x < PROJ_BLOCKS) {
        int lane = threadIdx.x & 63, wid = threadIdx.x >> 6;
        int grp = lane >> 4, col = lane & 15;
        int tile = blockIdx.x * 4 + wid;
        if (tile >= NN / 16) return;
        int n0 = tile * 16;

        f32x4 acc[8];
#pragma unroll
        for (int t = 0; t < 8; ++t) acc[t] = (f32x4){0.f, 0.f, 0.f, 0.f};

        const float* arow = x + (size_t)(n0 + col) * K_IN + grp * 8;
#pragma unroll
        for (int kt = 0; kt < 4; ++kt) {
            short8 a = ldfrag(arow + kt * 32);
#pragma unroll
            for (int t = 0; t < 8; ++t) {
                short8 b = ldfrag(W_l + (size_t)(t * 16 + col) * K_IN + kt * 32 + grp * 8);
                acc[t] = __builtin_amdgcn_mfma_f32_16x16x32_bf16(a, b, acc[t], 0, 0, 0);
            }
        }
#pragma unroll
        for (int j = 0; j < 4; ++j) {
            ushort8 o;
#pragma unroll
            for (int t = 0; t < 8; ++t) o[t] = (unsigned short)bf16r(acc[t][j]);
            *reinterpret_cast<ushort8*>(xbp + (size_t)(n0 + grp * 4 + j) * F + col * 8) = o;
        }
    } else {
        int e = (blockIdx.x - PROJ_BLOCKS) * 256 + threadIdx.x;
        if (e < NE) atomicAdd(&counts[ei[NE + e]], 1);
    }
}

// ---------------- CSR build ----------------
__global__ __launch_bounds__(1024) void scan1_kernel(const int* __restrict__ counts,
                                                     int* __restrict__ offs,
                                                     int* __restrict__ bsum) {
    __shared__ int wsum[16];
    int i = blockIdx.x * 1024 + threadIdx.x;
    int lane = threadIdx.x & 63, w = threadIdx.x >> 6;
    int v = (i < NN) ? counts[i] : 0;
    int x = v;
#pragma unroll
    for (int off = 1; off < 64; off <<= 1) {
        int y = __shfl_up(x, off, 64);
        if (lane >= off) x += y;
    }
    if (lane == 63) wsum[w] = x;
    __syncthreads();
    if (w == 0 && lane < 16) {
        int t = wsum[lane];
#pragma unroll
        for (int off = 1; off < 16; off <<= 1) {
            int y = __shfl_up(t, off, 16);
            if (lane >= off) t += y;
        }
        wsum[lane] = t;
    }
    __syncthreads();
    int woff = (w == 0) ? 0 : wsum[w - 1];
    if (i < NN) offs[i] = woff + x - v;
    if (threadIdx.x == 1023) bsum[blockIdx.x] = woff + x;
}

// scan3b: each block derives its own carry from bsum (<=64 entries)
__global__ __launch_bounds__(1024) void scan3b_kernel(int* __restrict__ offs,
                                                      const int* __restrict__ bsum,
                                                      int* __restrict__ cursor) {
    __shared__ int carry_s;
    if (threadIdx.x < 64) {
        int v = (threadIdx.x < blockIdx.x) ? bsum[threadIdx.x] : 0;
#pragma unroll
        for (int off = 32; off; off >>= 1) v += __shfl_xor(v, off, 64);
        if (threadIdx.x == 0) carry_s = v;
    }
    __syncthreads();
    int carry = carry_s;
    int i = blockIdx.x * 1024 + threadIdx.x;
    if (i < NN) {
        int o = offs[i] + carry;
        offs[i] = o;
        cursor[i] = o;
    }
    if (blockIdx.x == 0 && threadIdx.x == 0) offs[NN] = NE;
}

// perm2[p] = {edge, src}; tgts[p] = tgt
__global__ void scatter_kernel(const int* __restrict__ ei, int* __restrict__ cursor,
                               int2* __restrict__ perm2, int* __restrict__ tgts) {
    int e = blockIdx.x * blockDim.x + threadIdx.x;
    if (e < NE) {
        int src = ei[e];
        int tgt = ei[NE + e];
        int p = atomicAdd(&cursor[tgt], 1);
        int2 v; v.x = e; v.y = src;
        perm2[p] = v;
        tgts[p] = tgt;
    }
}

// ---------------- edge logits, sorted order, packed-bf16 xb, PACKED msg store ----------------
// msg packed layout: msg[p*F + col*8 + t] = bf16(xj+emb at f=t*16+col)
// MODE 1: write msg; MODE 0: no msg (fallback)
template<int MODE>
__global__ __launch_bounds__(256) void edge_logits_mfma(
    const int2* __restrict__ perm2, const int* __restrict__ tgts,
    const float* __restrict__ ea,
    const unsigned short* __restrict__ xbp, const float* __restrict__ W_e,
    const float* __restrict__ cb, const float* __restrict__ att,
    const float* __restrict__ att_sc, const float* __restrict__ ebias,
    float* __restrict__ lgs, unsigned short* __restrict__ msg) {
    int lane = threadIdx.x & 63, wid = threadIdx.x >> 6;
    int grp = lane >> 4, col = lane & 15;

    short8 B[8][2];
#pragma unroll
    for (int t = 0; t < 8; ++t)
#pragma unroll
        for (int kt = 0; kt < 2; ++kt)
            B[t][kt] = ldfrag(W_e + (size_t)(t * 16 + col) * ED + kt * 32 + grp * 8);

    float attv[8], cbe0[8], cbe1[8];
#pragma unroll
    for (int t = 0; t < 8; ++t) {
        int f = t * 16 + col;
        attv[t] = att[f];
        cbe0[t] = cb[f] + ebias[f * 2];
        cbe1[t] = cb[F + f] + ebias[f * 2 + 1];
    }
    float as0 = att_sc[0], as1 = att_sc[1];
    float2* lgs2 = reinterpret_cast<float2*>(lgs);

    for (int tile = blockIdx.x * 4 + wid; tile < NE / 16; tile += gridDim.x * 4) {
        int p0 = tile * 16;
        int2 pe = perm2[p0 + col];       // coalesced sequential
        int srcv = pe.y;
        int tgtv = tgts[p0 + col];       // coalesced sequential
        const float* arow = ea + (size_t)pe.x * ED + grp * 8;   // scattered rows
        short8 a0 = ldfrag(arow);
        short8 a1 = ldfrag(arow + 32);
        f32x4 acc[8];
#pragma unroll
        for (int t = 0; t < 8; ++t) acc[t] = (f32x4){0.f, 0.f, 0.f, 0.f};
#pragma unroll
        for (int t = 0; t < 8; ++t) {
            acc[t] = __builtin_amdgcn_mfma_f32_16x16x32_bf16(a0, B[t][0], acc[t], 0, 0, 0);
            acc[t] = __builtin_amdgcn_mfma_f32_16x16x32_bf16(a1, B[t][1], acc[t], 0, 0, 0);
        }
#pragma unroll
        for (int j = 0; j < 4; ++j) {
            int idx = grp * 4 + j;
            int src = __shfl(srcv, idx, 16);
            int tgt = __shfl(tgtv, idx, 16);  // ~uniform per tile (sorted)
            ushort8 xs = *reinterpret_cast<const ushort8*>(
                xbp + (size_t)src * F + col * 8);
            ushort8 xt = *reinterpret_cast<const ushort8*>(
                xbp + (size_t)tgt * F + col * 8);
            float q0 = 0.f, q1 = 0.f;
            ushort8 mvs;
#pragma unroll
            for (int t = 0; t < 8; ++t) {
                float mv = b2f(xs[t]) + acc[t][j];        // xj + emb
                mvs[t] = (unsigned short)bf16r(mv);
                float s = mv + b2f(xt[t]);
                float u0 = s + cbe0[t]; u0 = fmaxf(u0, NEG * u0);
                float u1 = s + cbe1[t]; u1 = fmaxf(u1, NEG * u1);
                q0 = fmaf(u0, attv[t], q0);
                q1 = fmaf(u1, attv[t], q1);
            }
            if (MODE >= 1)  // one 16B packed store instead of 8x2B
                *reinterpret_cast<ushort8*>(msg + (size_t)(p0 + idx) * F + col * 8) = mvs;
#pragma unroll
            for (int off = 8; off; off >>= 1) {
                q0 += __shfl_xor(q0, off, 16);
                q1 += __shfl_xor(q1, off, 16);
            }
            if (col == 0) {
                float2 o; o.x = q0 * as0; o.y = q1 * as1;
                lgs2[p0 + idx] = o;
            }
        }
    }
}

// ---------------- streaming aggregation from packed msg ----------------
// lane reads packed q = {2*lane, 2*lane+1}; f = (q&7)*16 + (q>>3)
__global__ __launch_bounds__(512) void agg_msg(
    const int* __restrict__ offs, const int2* __restrict__ perm2,
    const unsigned short* __restrict__ msg, const float* __restrict__ ebias,
    const float* __restrict__ lgs,
    float* __restrict__ out, float* __restrict__ alpha_out) {
    int lane = threadIdx.x & 63;
    int node = blockIdx.x * 8 + (threadIdx.x >> 6);
    if (node >= NN) return;
    int beg = offs[node], end = offs[node + 1];
    int deg = end - beg;
    float* orow = out + (size_t)node * (C * F);
    float2* orow2 = reinterpret_cast<float2*>(orow);
    if (deg == 0) {
        float2 z; z.x = 0.f; z.y = 0.f;
        orow2[lane] = z; orow2[64 + lane] = z;
        return;
    }
    const float2* lgs2 = reinterpret_cast<const float2*>(lgs);
    float2* al2 = reinterpret_cast<float2*>(alpha_out);

    float m0 = -FLTMAX, m1 = -FLTMAX;
    for (int j = beg + lane; j < end; j += 64) {
        float2 lg = lgs2[j];
        m0 = fmaxf(m0, lg.x); m1 = fmaxf(m1, lg.y);
    }
#pragma unroll
    for (int off = 32; off; off >>= 1) {
        m0 = fmaxf(m0, __shfl_xor(m0, off, 64));
        m1 = fmaxf(m1, __shfl_xor(m1, off, 64));
    }
    float su0 = 0.f, su1 = 0.f;
    for (int j = beg + lane; j < end; j += 64) {
        float2 lg = lgs2[j];
        su0 += __expf(lg.x - m0); su1 += __expf(lg.y - m1);
    }
#pragma unroll
    for (int off = 32; off; off >>= 1) {
        su0 += __shfl_xor(su0, off, 64);
        su1 += __shfl_xor(su1, off, 64);
    }
    float inv0 = 1.f / (su0 + 1e-16f), inv1 = 1.f / (su1 + 1e-16f);

    float g00 = 0.f, g01 = 0.f, g10 = 0.f, g11 = 0.f;
    for (int cb0 = beg; cb0 < end; cb0 += 64) {
        int cnt = min(64, end - cb0);
        int jl = cb0 + min(lane, cnt - 1);
        bool act = lane < cnt;
        int el = perm2[jl].x;
        float2 lgl = lgs2[jl];
        float e0v = act ? __expf(lgl.x - m0) : 0.f;
        float e1v = act ? __expf(lgl.y - m1) : 0.f;
        if (act) { float2 av; av.x = e0v * inv0; av.y = e1v * inv1; al2[el] = av; }
#pragma unroll 4
        for (int i = 0; i < cnt; ++i) {
            float a0 = __shfl(e0v, i, 64) * inv0;
            float a1 = __shfl(e1v, i, 64) * inv1;
            unsigned mv = *reinterpret_cast<const unsigned*>(
                msg + (size_t)(cb0 + i) * F + lane * 2);
            float f0 = __uint_as_float((mv & 0xffffu) << 16);
            float f1 = __uint_as_float(mv & 0xffff0000u);
            g00 = fmaf(a0, f0, g00); g01 = fmaf(a0, f1, g01);
            g10 = fmaf(a1, f0, g10); g11 = fmaf(a1, f1, g11);
        }
    }
    float sa0 = su0 * inv0, sa1 = su1 * inv1;
    // packed positions q0=2*lane (t even), q1=2*lane+1 -> f = (q&7)*16 + (q>>3)
    int q0i = 2 * lane;
    int f0i = (q0i & 7) * 16 + (q0i >> 3);
    int f1i = f0i + 16;                      // q1 = q0+1, t+1
    orow[f0i]       = g00 + ebias[f0i * 2] * sa0;
    orow[f1i]       = g01 + ebias[f1i * 2] * sa0;
    orow[F + f0i]   = g10 + ebias[f0i * 2 + 1] * sa1;
    orow[F + f1i]   = g11 + ebias[f1i * 2 + 1] * sa1;
}

// ---------------- fallback (never expected to run): gather agg + H + emb_gemm ----------------
__device__ __forceinline__ float xbval(const unsigned short* __restrict__ xbp,
                                       int n, int f) {
    return b2f(xbp[(size_t)n * F + (f & 15) * 8 + (f >> 4)]);
}

__global__ __launch_bounds__(512) void agg_fast(
    const int* __restrict__ offs, const int2* __restrict__ perm2,
    const float* __restrict__ ea, const unsigned short* __restrict__ xbp,
    const float* __restrict__ ebias, const float* __restrict__ lgs,
    float* __restrict__ out, float* __restrict__ alpha_out,
    float* __restrict__ H) {
    int lane = threadIdx.x & 63;
    int node = blockIdx.x * 8 + (threadIdx.x >> 6);
    if (node >= NN) return;
    int beg = offs[node], end = offs[node + 1];
    int deg = end - beg;
    float* orow = out + (size_t)node * (C * F);
    float* hrow = H + (size_t)node * (C * ED);

    if (deg == 0) {
        orow[lane] = 0.f; orow[64 + lane] = 0.f;
        orow[128 + lane] = 0.f; orow[192 + lane] = 0.f;
        if (lane < 32) { hrow[lane * 4] = 0.f; hrow[lane * 4 + 1] = 0.f;
                         hrow[lane * 4 + 2] = 0.f; hrow[lane * 4 + 3] = 0.f; }
        return;
    }
    const float2* lgs2 = reinterpret_cast<const float2*>(lgs);
    float2* al2 = reinterpret_cast<float2*>(alpha_out);

    float m0 = -FLTMAX, m1 = -FLTMAX;
    for (int j = beg + lane; j < end; j += 64) {
        float2 lg = lgs2[j];
        m0 = fmaxf(m0, lg.x); m1 = fmaxf(m1, lg.y);
    }
#pragma unroll
    for (int off = 32; off; off >>= 1) {
        m0 = fmaxf(m0, __shfl_xor(m0, off, 64));
        m1 = fmaxf(m1, __shfl_xor(m1, off, 64));
    }
    float s0 = 0.f, s1 = 0.f;
    for (int j = beg + lane; j < end; j += 64) {
        float2 lg = lgs2[j];
        s0 += __expf(lg.x - m0); s1 += __expf(lg.y - m1);
    }
#pragma unroll
    for (int off = 32; off; off >>= 1) {
        s0 += __shfl_xor(s0, off, 64);
        s1 += __shfl_xor(s1, off, 64);
    }
    float inv0 = 1.f / (s0 + 1e-16f), inv1 = 1.f / (s1 + 1e-16f);

    float h0 = 0.f, h1 = 0.f;
    float g00 = 0.f, g01 = 0.f, g10 = 0.f, g11 = 0.f;
    for (int j = beg; j < end; ++j) {
        int2 pe; pe.x = __builtin_amdgcn_readfirstlane(perm2[j].x);
        pe.y = __builtin_amdgcn_readfirstlane(perm2[j].y);
        float2 lg = lgs2[j];
        float a0 = __builtin_amdgcn_readfirstlane(__expf(lg.x - m0)) * inv0;
        float a1 = __builtin_amdgcn_readfirstlane(__expf(lg.y - m1)) * inv1;
        if (lane == 0) { float2 av; av.x = a0; av.y = a1; al2[pe.x] = av; }
        float av = ea[(size_t)pe.x * ED + lane];
        h0 = fmaf(a0, av, h0); h1 = fmaf(a1, av, h1);
        float xv0 = xbval(xbp, pe.y, lane);
        float xv1 = xbval(xbp, pe.y, 64 + lane);
        g00 = fmaf(a0, xv0, g00); g01 = fmaf(a1, xv0, g01);
        g10 = fmaf(a0, xv1, g10); g11 = fmaf(a1, xv1, g11);
    }
    hrow[lane] = h0; hrow[64 + lane] = h1;
    float sa0 = s0 * inv0, sa1 = s1 * inv1;
    orow[lane]       = g00 + ebias[lane * 2] * sa0;
    orow[64 + lane]  = g10 + ebias[(64 + lane) * 2] * sa0;
    orow[128 + lane] = g01 + ebias[lane * 2 + 1] * sa1;
    orow[192 + lane] = g11 + ebias[(64 + lane) * 2 + 1] * sa1;
}

__global__ __launch_bounds__(512) void emb_gemm(const float* __restrict__ H,
                                                const float* __restrict__ W_e,
                                                float* __restrict__ out) {
    __shared__ float WeT[ED][F];
    for (int i = threadIdx.x; i < ED * F; i += 512) {
        int f = i & (F - 1), k = i >> 7;
        WeT[k][f] = W_e[(size_t)f * ED + k];
    }
    __syncthreads();
    int lane = threadIdx.x & 63, wid = threadIdx.x >> 6;
    const int R = NN * C;
    for (int row = blockIdx.x * 8 + wid; row < R; row += gridDim.x * 8) {
        float h = H[(size_t)row * ED + lane];
        float m0 = 0.f, m1 = 0.f;
#pragma unroll
        for (int k = 0; k < ED; ++k) {
            float hk = __shfl(h, k, 64);
            m0 = fmaf(hk, WeT[k][lane], m0);
            m1 = fmaf(hk, WeT[k][lane + 64], m1);
        }
        float* op = out + (size_t)row * F;
        op[lane] += m0;
        op[lane + 64] += m1;
    }
}

extern "C" void kernel_launch(void* const* d_in, const int* in_sizes, int n_in,
                              void* d_out, int out_size, void* d_ws, size_t ws_size,
                              hipStream_t stream) {
    const float* x      = (const float*)d_in[0];
    const int*   ei     = (const int*)d_in[1];
    const float* ea     = (const float*)d_in[2];
    const float* W_l    = (const float*)d_in[3];
    const float* cb     = (const float*)d_in[4];
    const float* att    = (const float*)d_in[5];
    const float* att_sc = (const float*)d_in[6];
    const float* W_e    = (const float*)d_in[7];
    const float* ebias  = (const float*)d_in[8];

    float* out = (float*)d_out;
    float* alpha_out = out + (size_t)NN * C * F;

    float* ws = (float*)d_ws;
    unsigned short* xbp = (unsigned short*)ws;   // 12.8 MB (region reserves 25.6)
    float* lgs  = ws + 6400000;                  // 4 MB
    int* ibase  = (int*)(ws + 7400000);
    int* counts = ibase;                         // NN (becomes cursor)
    int* offs   = ibase + NN;                    // NN+1 (pad to 100064)
    int* bsum   = ibase + 100064;                // 64
    int* tgts   = ibase + 100128;                // NE
    int2* perm2 = (int2*)(ibase + 100128 + NE);  // NE int2
    char* tail = (char*)(ibase + 100128 + 3 * NE);
    tail = (char*)(((size_t)tail + 15) & ~(size_t)15);
    size_t head_bytes = (size_t)(tail - (char*)d_ws);
    size_t msg_bytes = (size_t)NE * F * 2;       // 128 MB
    bool use_msg = ws_size >= head_bytes + msg_bytes + 64;
    unsigned short* msg = (unsigned short*)tail;
    float* H = (float*)tail;

    hipMemsetAsync(counts, 0, NN * sizeof(int), stream);

    proj_hist<<<PROJ_BLOCKS + HIST_BLOCKS, 256, 0, stream>>>(x, W_l, xbp, ei, counts);

    const int NB = (NN + 1023) / 1024; // 49
    scan1_kernel<<<NB, 1024, 0, stream>>>(counts, offs, bsum);
    scan3b_kernel<<<NB, 1024, 0, stream>>>(offs, bsum, counts); // counts = cursor
    scatter_kernel<<<(NE + 255) / 256, 256, 0, stream>>>(ei, counts, perm2, tgts);

    if (use_msg) {
        edge_logits_mfma<1><<<2048, 256, 0, stream>>>(perm2, tgts, ea, xbp, W_e,
                                                      cb, att, att_sc, ebias,
                                                      lgs, msg);
        agg_msg<<<(NN + 7) / 8, 512, 0, stream>>>(offs, perm2, msg, ebias, lgs,
                                                  out, alpha_out);
    } else {
        edge_logits_mfma<0><<<2048, 256, 0, stream>>>(perm2, tgts, ea, xbp, W_e,
                                                      cb, att, att_sc, ebias,
                                                      lgs, (unsigned short*)0);
        agg_fast<<<(NN + 7) / 8, 512, 0, stream>>>(offs, perm2, ea, xbp, ebias, lgs,
                                                   out, alpha_out, H);
        emb_gemm<<<1024, 512, 0, stream>>>(H, W_e, out);
    }
}

// Round 17
// 253.761 us; speedup vs baseline: 1.0338x; 1.0338x over previous
//
#include <hip/hip_runtime.h>
#include <hip/hip_bf16.h>

#define NN 50000
#define NE 500000
#define F 128
#define K_IN 128
#define ED 64
#define C 2
#define NEG 0.2f
#define FLTMAX 3.402823466e38f
#define PROJ_BLOCKS 782
#define HIST_BLOCKS 1954

typedef __attribute__((ext_vector_type(8))) short short8;
typedef __attribute__((ext_vector_type(8))) unsigned short ushort8;
typedef __attribute__((ext_vector_type(4))) float f32x4;

__device__ __forceinline__ short bf16r(float f) {
    unsigned u = __float_as_uint(f);
    unsigned r = (u + 0x7fffu + ((u >> 16) & 1u)) >> 16;
    return (short)r;
}

__device__ __forceinline__ float b2f(unsigned short v) {
    return __uint_as_float(((unsigned)v) << 16);
}

__device__ __forceinline__ short8 ldfrag(const float* base) {
    const float4* p = reinterpret_cast<const float4*>(base);
    float4 v0 = p[0], v1 = p[1];
    short8 r;
    r[0] = bf16r(v0.x); r[1] = bf16r(v0.y); r[2] = bf16r(v0.z); r[3] = bf16r(v0.w);
    r[4] = bf16r(v1.x); r[5] = bf16r(v1.y); r[6] = bf16r(v1.z); r[7] = bf16r(v1.w);
    return r;
}

// packed xb layout: xbp[n*128 + col*8 + t] = bf16(x_base[n][t*16+col])
// ---------------- fused: proj (blocks < PROJ_BLOCKS) + hist (rest) ----------------
__global__ __launch_bounds__(256) void proj_hist(const float* __restrict__ x,
                                                 const float* __restrict__ W_l,
                                                 unsigned short* __restrict__ xbp,
                                                 const int* __restrict__ ei,
                                                 int* __restrict__ counts) {
    if (blockIdx.x < PROJ_BLOCKS) {
        int lane = threadIdx.x & 63, wid = threadIdx.x >> 6;
        int grp = lane >> 4, col = lane & 15;
        int tile = blockIdx.x * 4 + wid;
        if (tile >= NN / 16) return;
        int n0 = tile * 16;

        f32x4 acc[8];
#pragma unroll
        for (int t = 0; t < 8; ++t) acc[t] = (f32x4){0.f, 0.f, 0.f, 0.f};

        const float* arow = x + (size_t)(n0 + col) * K_IN + grp * 8;
#pragma unroll
        for (int kt = 0; kt < 4; ++kt) {
            short8 a = ldfrag(arow + kt * 32);
#pragma unroll
            for (int t = 0; t < 8; ++t) {
                short8 b = ldfrag(W_l + (size_t)(t * 16 + col) * K_IN + kt * 32 + grp * 8);
                acc[t] = __builtin_amdgcn_mfma_f32_16x16x32_bf16(a, b, acc[t], 0, 0, 0);
            }
        }
#pragma unroll
        for (int j = 0; j < 4; ++j) {
            ushort8 o;
#pragma unroll
            for (int t = 0; t < 8; ++t) o[t] = (unsigned short)bf16r(acc[t][j]);
            *reinterpret_cast<ushort8*>(xbp + (size_t)(n0 + grp * 4 + j) * F + col * 8) = o;
        }
    } else {
        int e = (blockIdx.x - PROJ_BLOCKS) * 256 + threadIdx.x;
        if (e < NE) atomicAdd(&counts[ei[NE + e]], 1);
    }
}

// ---------------- CSR build ----------------
__global__ __launch_bounds__(1024) void scan1_kernel(const int* __restrict__ counts,
                                                     int* __restrict__ offs,
                                                     int* __restrict__ bsum) {
    __shared__ int wsum[16];
    int i = blockIdx.x * 1024 + threadIdx.x;
    int lane = threadIdx.x & 63, w = threadIdx.x >> 6;
    int v = (i < NN) ? counts[i] : 0;
    int x = v;
#pragma unroll
    for (int off = 1; off < 64; off <<= 1) {
        int y = __shfl_up(x, off, 64);
        if (lane >= off) x += y;
    }
    if (lane == 63) wsum[w] = x;
    __syncthreads();
    if (w == 0 && lane < 16) {
        int t = wsum[lane];
#pragma unroll
        for (int off = 1; off < 16; off <<= 1) {
            int y = __shfl_up(t, off, 16);
            if (lane >= off) t += y;
        }
        wsum[lane] = t;
    }
    __syncthreads();
    int woff = (w == 0) ? 0 : wsum[w - 1];
    if (i < NN) offs[i] = woff + x - v;
    if (threadIdx.x == 1023) bsum[blockIdx.x] = woff + x;
}

// scan3b: each block derives its own carry from bsum (<=64 entries)
__global__ __launch_bounds__(1024) void scan3b_kernel(int* __restrict__ offs,
                                                      const int* __restrict__ bsum,
                                                      int* __restrict__ cursor) {
    __shared__ int carry_s;
    if (threadIdx.x < 64) {
        int v = (threadIdx.x < blockIdx.x) ? bsum[threadIdx.x] : 0;
#pragma unroll
        for (int off = 32; off; off >>= 1) v += __shfl_xor(v, off, 64);
        if (threadIdx.x == 0) carry_s = v;
    }
    __syncthreads();
    int carry = carry_s;
    int i = blockIdx.x * 1024 + threadIdx.x;
    if (i < NN) {
        int o = offs[i] + carry;
        offs[i] = o;
        cursor[i] = o;
    }
    if (blockIdx.x == 0 && threadIdx.x == 0) offs[NN] = NE;
}

// perm2[p] = {edge, src}; tgts[p] = tgt
__global__ void scatter_kernel(const int* __restrict__ ei, int* __restrict__ cursor,
                               int2* __restrict__ perm2, int* __restrict__ tgts) {
    int e = blockIdx.x * blockDim.x + threadIdx.x;
    if (e < NE) {
        int src = ei[e];
        int tgt = ei[NE + e];
        int p = atomicAdd(&cursor[tgt], 1);
        int2 v; v.x = e; v.y = src;
        perm2[p] = v;
        tgts[p] = tgt;
    }
}

// ---------------- edge logits: xs gathers prefetched above the MFMA block ----------------
// msg packed layout: msg[p*F + col*8 + t] = bf16(xj+emb at f=t*16+col)
// MODE 1: write msg; MODE 0: no msg (fallback)
template<int MODE>
__global__ __launch_bounds__(256) void edge_logits_mfma(
    const int2* __restrict__ perm2, const int* __restrict__ tgts,
    const float* __restrict__ ea,
    const unsigned short* __restrict__ xbp, const float* __restrict__ W_e,
    const float* __restrict__ cb, const float* __restrict__ att,
    const float* __restrict__ att_sc, const float* __restrict__ ebias,
    float* __restrict__ lgs, unsigned short* __restrict__ msg) {
    int lane = threadIdx.x & 63, wid = threadIdx.x >> 6;
    int grp = lane >> 4, col = lane & 15;

    short8 B[8][2];
#pragma unroll
    for (int t = 0; t < 8; ++t)
#pragma unroll
        for (int kt = 0; kt < 2; ++kt)
            B[t][kt] = ldfrag(W_e + (size_t)(t * 16 + col) * ED + kt * 32 + grp * 8);

    float attv[8], cbe0[8], cbe1[8];
#pragma unroll
    for (int t = 0; t < 8; ++t) {
        int f = t * 16 + col;
        attv[t] = att[f];
        cbe0[t] = cb[f] + ebias[f * 2];
        cbe1[t] = cb[F + f] + ebias[f * 2 + 1];
    }
    float as0 = att_sc[0], as1 = att_sc[1];
    float2* lgs2 = reinterpret_cast<float2*>(lgs);

    for (int tile = blockIdx.x * 4 + wid; tile < NE / 16; tile += gridDim.x * 4) {
        int p0 = tile * 16;
        int2 pe = perm2[p0 + col];       // coalesced sequential
        int srcv = pe.y;
        int tgtv = tgts[p0 + col];       // coalesced sequential
        const float* arow = ea + (size_t)pe.x * ED + grp * 8;   // scattered rows
        short8 a0 = ldfrag(arow);
        short8 a1 = ldfrag(arow + 32);

        // prefetch the 4 random xs rows BEFORE the MFMA block so their
        // L2/L3 latency hides under the ea-wait + 16 MFMAs (16 VGPRs)
        int srcs[4], tgti[4];
        ushort8 xsv[4];
#pragma unroll
        for (int j = 0; j < 4; ++j) {
            int idx = grp * 4 + j;
            srcs[j] = __shfl(srcv, idx, 16);
            tgti[j] = __shfl(tgtv, idx, 16);
            xsv[j] = *reinterpret_cast<const ushort8*>(
                xbp + (size_t)srcs[j] * F + col * 8);
        }

        f32x4 acc[8];
#pragma unroll
        for (int t = 0; t < 8; ++t) acc[t] = (f32x4){0.f, 0.f, 0.f, 0.f};
#pragma unroll
        for (int t = 0; t < 8; ++t) {
            acc[t] = __builtin_amdgcn_mfma_f32_16x16x32_bf16(a0, B[t][0], acc[t], 0, 0, 0);
            acc[t] = __builtin_amdgcn_mfma_f32_16x16x32_bf16(a1, B[t][1], acc[t], 0, 0, 0);
        }
#pragma unroll
        for (int j = 0; j < 4; ++j) {
            int idx = grp * 4 + j;
            ushort8 xs = xsv[j];
            ushort8 xt = *reinterpret_cast<const ushort8*>(
                xbp + (size_t)tgti[j] * F + col * 8);   // ~uniform -> L1 hit
            float q0 = 0.f, q1 = 0.f;
            ushort8 mvs;
#pragma unroll
            for (int t = 0; t < 8; ++t) {
                float mv = b2f(xs[t]) + acc[t][j];        // xj + emb
                mvs[t] = (unsigned short)bf16r(mv);
                float s = mv + b2f(xt[t]);
                float u0 = s + cbe0[t]; u0 = fmaxf(u0, NEG * u0);
                float u1 = s + cbe1[t]; u1 = fmaxf(u1, NEG * u1);
                q0 = fmaf(u0, attv[t], q0);
                q1 = fmaf(u1, attv[t], q1);
            }
            if (MODE >= 1)  // one 16B packed store
                *reinterpret_cast<ushort8*>(msg + (size_t)(p0 + idx) * F + col * 8) = mvs;
#pragma unroll
            for (int off = 8; off; off >>= 1) {
                q0 += __shfl_xor(q0, off, 16);
                q1 += __shfl_xor(q1, off, 16);
            }
            if (col == 0) {
                float2 o; o.x = q0 * as0; o.y = q1 * as1;
                lgs2[p0 + idx] = o;
            }
        }
    }
}

// ---------------- streaming aggregation from packed msg ----------------
// lane reads packed q = {2*lane, 2*lane+1}; f = (q&7)*16 + (q>>3)
__global__ __launch_bounds__(512) void agg_msg(
    const int* __restrict__ offs, const int2* __restrict__ perm2,
    const unsigned short* __restrict__ msg, const float* __restrict__ ebias,
    const float* __restrict__ lgs,
    float* __restrict__ out, float* __restrict__ alpha_out) {
    int lane = threadIdx.x & 63;
    int node = blockIdx.x * 8 + (threadIdx.x >> 6);
    if (node >= NN) return;
    int beg = offs[node], end = offs[node + 1];
    int deg = end - beg;
    float* orow = out + (size_t)node * (C * F);
    float2* orow2 = reinterpret_cast<float2*>(orow);
    if (deg == 0) {
        float2 z; z.x = 0.f; z.y = 0.f;
        orow2[lane] = z; orow2[64 + lane] = z;
        return;
    }
    const float2* lgs2 = reinterpret_cast<const float2*>(lgs);
    float2* al2 = reinterpret_cast<float2*>(alpha_out);

    float m0 = -FLTMAX, m1 = -FLTMAX;
    for (int j = beg + lane; j < end; j += 64) {
        float2 lg = lgs2[j];
        m0 = fmaxf(m0, lg.x); m1 = fmaxf(m1, lg.y);
    }
#pragma unroll
    for (int off = 32; off; off >>= 1) {
        m0 = fmaxf(m0, __shfl_xor(m0, off, 64));
        m1 = fmaxf(m1, __shfl_xor(m1, off, 64));
    }
    float su0 = 0.f, su1 = 0.f;
    for (int j = beg + lane; j < end; j += 64) {
        float2 lg = lgs2[j];
        su0 += __expf(lg.x - m0); su1 += __expf(lg.y - m1);
    }
#pragma unroll
    for (int off = 32; off; off >>= 1) {
        su0 += __shfl_xor(su0, off, 64);
        su1 += __shfl_xor(su1, off, 64);
    }
    float inv0 = 1.f / (su0 + 1e-16f), inv1 = 1.f / (su1 + 1e-16f);

    float g00 = 0.f, g01 = 0.f, g10 = 0.f, g11 = 0.f;
    for (int cb0 = beg; cb0 < end; cb0 += 64) {
        int cnt = min(64, end - cb0);
        int jl = cb0 + min(lane, cnt - 1);
        bool act = lane < cnt;
        int el = perm2[jl].x;
        float2 lgl = lgs2[jl];
        float e0v = act ? __expf(lgl.x - m0) : 0.f;
        float e1v = act ? __expf(lgl.y - m1) : 0.f;
        if (act) { float2 av; av.x = e0v * inv0; av.y = e1v * inv1; al2[el] = av; }
#pragma unroll 4
        for (int i = 0; i < cnt; ++i) {
            float a0 = __shfl(e0v, i, 64) * inv0;
            float a1 = __shfl(e1v, i, 64) * inv1;
            unsigned mv = *reinterpret_cast<const unsigned*>(
                msg + (size_t)(cb0 + i) * F + lane * 2);
            float f0 = __uint_as_float((mv & 0xffffu) << 16);
            float f1 = __uint_as_float(mv & 0xffff0000u);
            g00 = fmaf(a0, f0, g00); g01 = fmaf(a0, f1, g01);
            g10 = fmaf(a1, f0, g10); g11 = fmaf(a1, f1, g11);
        }
    }
    float sa0 = su0 * inv0, sa1 = su1 * inv1;
    // packed positions q0=2*lane (t even), q1=2*lane+1 -> f = (q&7)*16 + (q>>3)
    int q0i = 2 * lane;
    int f0i = (q0i & 7) * 16 + (q0i >> 3);
    int f1i = f0i + 16;                      // q1 = q0+1, t+1
    orow[f0i]       = g00 + ebias[f0i * 2] * sa0;
    orow[f1i]       = g01 + ebias[f1i * 2] * sa0;
    orow[F + f0i]   = g10 + ebias[f0i * 2 + 1] * sa1;
    orow[F + f1i]   = g11 + ebias[f1i * 2 + 1] * sa1;
}

// ---------------- fallback (never expected to run): gather agg + H + emb_gemm ----------------
__device__ __forceinline__ float xbval(const unsigned short* __restrict__ xbp,
                                       int n, int f) {
    return b2f(xbp[(size_t)n * F + (f & 15) * 8 + (f >> 4)]);
}

__global__ __launch_bounds__(512) void agg_fast(
    const int* __restrict__ offs, const int2* __restrict__ perm2,
    const float* __restrict__ ea, const unsigned short* __restrict__ xbp,
    const float* __restrict__ ebias, const float* __restrict__ lgs,
    float* __restrict__ out, float* __restrict__ alpha_out,
    float* __restrict__ H) {
    int lane = threadIdx.x & 63;
    int node = blockIdx.x * 8 + (threadIdx.x >> 6);
    if (node >= NN) return;
    int beg = offs[node], end = offs[node + 1];
    int deg = end - beg;
    float* orow = out + (size_t)node * (C * F);
    float* hrow = H + (size_t)node * (C * ED);

    if (deg == 0) {
        orow[lane] = 0.f; orow[64 + lane] = 0.f;
        orow[128 + lane] = 0.f; orow[192 + lane] = 0.f;
        if (lane < 32) { hrow[lane * 4] = 0.f; hrow[lane * 4 + 1] = 0.f;
                         hrow[lane * 4 + 2] = 0.f; hrow[lane * 4 + 3] = 0.f; }
        return;
    }
    const float2* lgs2 = reinterpret_cast<const float2*>(lgs);
    float2* al2 = reinterpret_cast<float2*>(alpha_out);

    float m0 = -FLTMAX, m1 = -FLTMAX;
    for (int j = beg + lane; j < end; j += 64) {
        float2 lg = lgs2[j];
        m0 = fmaxf(m0, lg.x); m1 = fmaxf(m1, lg.y);
    }
#pragma unroll
    for (int off = 32; off; off >>= 1) {
        m0 = fmaxf(m0, __shfl_xor(m0, off, 64));
        m1 = fmaxf(m1, __shfl_xor(m1, off, 64));
    }
    float s0 = 0.f, s1 = 0.f;
    for (int j = beg + lane; j < end; j += 64) {
        float2 lg = lgs2[j];
        s0 += __expf(lg.x - m0); s1 += __expf(lg.y - m1);
    }
#pragma unroll
    for (int off = 32; off; off >>= 1) {
        s0 += __shfl_xor(s0, off, 64);
        s1 += __shfl_xor(s1, off, 64);
    }
    float inv0 = 1.f / (s0 + 1e-16f), inv1 = 1.f / (s1 + 1e-16f);

    float h0 = 0.f, h1 = 0.f;
    float g00 = 0.f, g01 = 0.f, g10 = 0.f, g11 = 0.f;
    for (int j = beg; j < end; ++j) {
        int2 pe; pe.x = __builtin_amdgcn_readfirstlane(perm2[j].x);
        pe.y = __builtin_amdgcn_readfirstlane(perm2[j].y);
        float2 lg = lgs2[j];
        float a0 = __builtin_amdgcn_readfirstlane(__expf(lg.x - m0)) * inv0;
        float a1 = __builtin_amdgcn_readfirstlane(__expf(lg.y - m1)) * inv1;
        if (lane == 0) { float2 av; av.x = a0; av.y = a1; al2[pe.x] = av; }
        float av = ea[(size_t)pe.x * ED + lane];
        h0 = fmaf(a0, av, h0); h1 = fmaf(a1, av, h1);
        float xv0 = xbval(xbp, pe.y, lane);
        float xv1 = xbval(xbp, pe.y, 64 + lane);
        g00 = fmaf(a0, xv0, g00); g01 = fmaf(a1, xv0, g01);
        g10 = fmaf(a0, xv1, g10); g11 = fmaf(a1, xv1, g11);
    }
    hrow[lane] = h0; hrow[64 + lane] = h1;
    float sa0 = s0 * inv0, sa1 = s1 * inv1;
    orow[lane]       = g00 + ebias[lane * 2] * sa0;
    orow[64 + lane]  = g10 + ebias[(64 + lane) * 2] * sa0;
    orow[128 + lane] = g01 + ebias[lane * 2 + 1] * sa1;
    orow[192 + lane] = g11 + ebias[(64 + lane) * 2 + 1] * sa1;
}

__global__ __launch_bounds__(512) void emb_gemm(const float* __restrict__ H,
                                                const float* __restrict__ W_e,
                                                float* __restrict__ out) {
    __shared__ float WeT[ED][F];
    for (int i = threadIdx.x; i < ED * F; i += 512) {
        int f = i & (F - 1), k = i >> 7;
        WeT[k][f] = W_e[(size_t)f * ED + k];
    }
    __syncthreads();
    int lane = threadIdx.x & 63, wid = threadIdx.x >> 6;
    const int R = NN * C;
    for (int row = blockIdx.x * 8 + wid; row < R; row += gridDim.x * 8) {
        float h = H[(size_t)row * ED + lane];
        float m0 = 0.f, m1 = 0.f;
#pragma unroll
        for (int k = 0; k < ED; ++k) {
            float hk = __shfl(h, k, 64);
            m0 = fmaf(hk, WeT[k][lane], m0);
            m1 = fmaf(hk, WeT[k][lane + 64], m1);
        }
        float* op = out + (size_t)row * F;
        op[lane] += m0;
        op[lane + 64] += m1;
    }
}

extern "C" void kernel_launch(void* const* d_in, const int* in_sizes, int n_in,
                              void* d_out, int out_size, void* d_ws, size_t ws_size,
                              hipStream_t stream) {
    const float* x      = (const float*)d_in[0];
    const int*   ei     = (const int*)d_in[1];
    const float* ea     = (const float*)d_in[2];
    const float* W_l    = (const float*)d_in[3];
    const float* cb     = (const float*)d_in[4];
    const float* att    = (const float*)d_in[5];
    const float* att_sc = (const float*)d_in[6];
    const float* W_e    = (const float*)d_in[7];
    const float* ebias  = (const float*)d_in[8];

    float* out = (float*)d_out;
    float* alpha_out = out + (size_t)NN * C * F;

    float* ws = (float*)d_ws;
    unsigned short* xbp = (unsigned short*)ws;   // 12.8 MB (region reserves 25.6)
    float* lgs  = ws + 6400000;                  // 4 MB
    int* ibase  = (int*)(ws + 7400000);
    int* counts = ibase;                         // NN (becomes cursor)
    int* offs   = ibase + NN;                    // NN+1 (pad to 100064)
    int* bsum   = ibase + 100064;                // 64
    int* tgts   = ibase + 100128;                // NE
    int2* perm2 = (int2*)(ibase + 100128 + NE);  // NE int2
    char* tail = (char*)(ibase + 100128 + 3 * NE);
    tail = (char*)(((size_t)tail + 15) & ~(size_t)15);
    size_t head_bytes = (size_t)(tail - (char*)d_ws);
    size_t msg_bytes = (size_t)NE * F * 2;       // 128 MB
    bool use_msg = ws_size >= head_bytes + msg_bytes + 64;
    unsigned short* msg = (unsigned short*)tail;
    float* H = (float*)tail;

    hipMemsetAsync(counts, 0, NN * sizeof(int), stream);

    proj_hist<<<PROJ_BLOCKS + HIST_BLOCKS, 256, 0, stream>>>(x, W_l, xbp, ei, counts);

    const int NB = (NN + 1023) / 1024; // 49
    scan1_kernel<<<NB, 1024, 0, stream>>>(counts, offs, bsum);
    scan3b_kernel<<<NB, 1024, 0, stream>>>(offs, bsum, counts); // counts = cursor
    scatter_kernel<<<(NE + 255) / 256, 256, 0, stream>>>(ei, counts, perm2, tgts);

    if (use_msg) {
        edge_logits_mfma<1><<<2048, 256, 0, stream>>>(perm2, tgts, ea, xbp, W_e,
                                                      cb, att, att_sc, ebias,
                                                      lgs, msg);
        agg_msg<<<(NN + 7) / 8, 512, 0, stream>>>(offs, perm2, msg, ebias, lgs,
                                                  out, alpha_out);
    } else {
        edge_logits_mfma<0><<<2048, 256, 0, stream>>>(perm2, tgts, ea, xbp, W_e,
                                                      cb, att, att_sc, ebias,
                                                      lgs, (unsigned short*)0);
        agg_fast<<<(NN + 7) / 8, 512, 0, stream>>>(offs, perm2, ea, xbp, ebias, lgs,
                                                   out, alpha_out, H);
        emb_gemm<<<1024, 512, 0, stream>>>(H, W_e, out);
    }
}

// Round 18
// 252.545 us; speedup vs baseline: 1.0388x; 1.0048x over previous
//
#include <hip/hip_runtime.h>
#include <hip/hip_bf16.h>

#define NN 50000
#define NE 500000
#define F 128
#define K_IN 128
#define ED 64
#define C 2
#define NEG 0.2f
#define FLTMAX 3.402823466e38f
#define PROJ_BLOCKS 782
#define HIST_BLOCKS 1954

typedef __attribute__((ext_vector_type(8))) short short8;
typedef __attribute__((ext_vector_type(8))) unsigned short ushort8;
typedef __attribute__((ext_vector_type(4))) float f32x4;

__device__ __forceinline__ short bf16r(float f) {
    unsigned u = __float_as_uint(f);
    unsigned r = (u + 0x7fffu + ((u >> 16) & 1u)) >> 16;
    return (short)r;
}

__device__ __forceinline__ float b2f(unsigned short v) {
    return __uint_as_float(((unsigned)v) << 16);
}

__device__ __forceinline__ short8 ldfrag(const float* base) {
    const float4* p = reinterpret_cast<const float4*>(base);
    float4 v0 = p[0], v1 = p[1];
    short8 r;
    r[0] = bf16r(v0.x); r[1] = bf16r(v0.y); r[2] = bf16r(v0.z); r[3] = bf16r(v0.w);
    r[4] = bf16r(v1.x); r[5] = bf16r(v1.y); r[6] = bf16r(v1.z); r[7] = bf16r(v1.w);
    return r;
}

__device__ __forceinline__ short8 cvt8(float4 v0, float4 v1) {
    short8 r;
    r[0] = bf16r(v0.x); r[1] = bf16r(v0.y); r[2] = bf16r(v0.z); r[3] = bf16r(v0.w);
    r[4] = bf16r(v1.x); r[5] = bf16r(v1.y); r[6] = bf16r(v1.z); r[7] = bf16r(v1.w);
    return r;
}

// packed xb layout: xbp[n*128 + col*8 + t] = bf16(x_base[n][t*16+col])
// ---------------- fused: proj (blocks < PROJ_BLOCKS) + hist (rest) ----------------
__global__ __launch_bounds__(256) void proj_hist(const float* __restrict__ x,
                                                 const float* __restrict__ W_l,
                                                 unsigned short* __restrict__ xbp,
                                                 const int* __restrict__ ei,
                                                 int* __restrict__ counts) {
    if (blockIdx.x < PROJ_BLOCKS) {
        int lane = threadIdx.x & 63, wid = threadIdx.x >> 6;
        int grp = lane >> 4, col = lane & 15;
        int tile = blockIdx.x * 4 + wid;
        if (tile >= NN / 16) return;
        int n0 = tile * 16;

        f32x4 acc[8];
#pragma unroll
        for (int t = 0; t < 8; ++t) acc[t] = (f32x4){0.f, 0.f, 0.f, 0.f};

        const float* arow = x + (size_t)(n0 + col) * K_IN + grp * 8;
#pragma unroll
        for (int kt = 0; kt < 4; ++kt) {
            short8 a = ldfrag(arow + kt * 32);
#pragma unroll
            for (int t = 0; t < 8; ++t) {
                short8 b = ldfrag(W_l + (size_t)(t * 16 + col) * K_IN + kt * 32 + grp * 8);
                acc[t] = __builtin_amdgcn_mfma_f32_16x16x32_bf16(a, b, acc[t], 0, 0, 0);
            }
        }
#pragma unroll
        for (int j = 0; j < 4; ++j) {
            ushort8 o;
#pragma unroll
            for (int t = 0; t < 8; ++t) o[t] = (unsigned short)bf16r(acc[t][j]);
            *reinterpret_cast<ushort8*>(xbp + (size_t)(n0 + grp * 4 + j) * F + col * 8) = o;
        }
    } else {
        int e = (blockIdx.x - PROJ_BLOCKS) * 256 + threadIdx.x;
        if (e < NE) atomicAdd(&counts[ei[NE + e]], 1);
    }
}

// ---------------- CSR build ----------------
__global__ __launch_bounds__(1024) void scan1_kernel(const int* __restrict__ counts,
                                                     int* __restrict__ offs,
                                                     int* __restrict__ bsum) {
    __shared__ int wsum[16];
    int i = blockIdx.x * 1024 + threadIdx.x;
    int lane = threadIdx.x & 63, w = threadIdx.x >> 6;
    int v = (i < NN) ? counts[i] : 0;
    int x = v;
#pragma unroll
    for (int off = 1; off < 64; off <<= 1) {
        int y = __shfl_up(x, off, 64);
        if (lane >= off) x += y;
    }
    if (lane == 63) wsum[w] = x;
    __syncthreads();
    if (w == 0 && lane < 16) {
        int t = wsum[lane];
#pragma unroll
        for (int off = 1; off < 16; off <<= 1) {
            int y = __shfl_up(t, off, 16);
            if (lane >= off) t += y;
        }
        wsum[lane] = t;
    }
    __syncthreads();
    int woff = (w == 0) ? 0 : wsum[w - 1];
    if (i < NN) offs[i] = woff + x - v;
    if (threadIdx.x == 1023) bsum[blockIdx.x] = woff + x;
}

// scan3b: each block derives its own carry from bsum (<=64 entries)
__global__ __launch_bounds__(1024) void scan3b_kernel(int* __restrict__ offs,
                                                      const int* __restrict__ bsum,
                                                      int* __restrict__ cursor) {
    __shared__ int carry_s;
    if (threadIdx.x < 64) {
        int v = (threadIdx.x < blockIdx.x) ? bsum[threadIdx.x] : 0;
#pragma unroll
        for (int off = 32; off; off >>= 1) v += __shfl_xor(v, off, 64);
        if (threadIdx.x == 0) carry_s = v;
    }
    __syncthreads();
    int carry = carry_s;
    int i = blockIdx.x * 1024 + threadIdx.x;
    if (i < NN) {
        int o = offs[i] + carry;
        offs[i] = o;
        cursor[i] = o;
    }
    if (blockIdx.x == 0 && threadIdx.x == 0) offs[NN] = NE;
}

// perm2[p] = {edge, src}; tgts[p] = tgt
__global__ void scatter_kernel(const int* __restrict__ ei, int* __restrict__ cursor,
                               int2* __restrict__ perm2, int* __restrict__ tgts) {
    int e = blockIdx.x * blockDim.x + threadIdx.x;
    if (e < NE) {
        int src = ei[e];
        int tgt = ei[NE + e];
        int p = atomicAdd(&cursor[tgt], 1);
        int2 v; v.x = e; v.y = src;
        perm2[p] = v;
        tgts[p] = tgt;
    }
}

// ---------------- edge logits: 1-deep ea prefetch + xs hoist ----------------
// msg packed layout: msg[p*F + col*8 + t] = bf16(xj+emb at f=t*16+col)
// MODE 1: write msg; MODE 0: no msg (fallback)
template<int MODE>
__global__ __launch_bounds__(256) void edge_logits_mfma(
    const int2* __restrict__ perm2, const int* __restrict__ tgts,
    const float* __restrict__ ea,
    const unsigned short* __restrict__ xbp, const float* __restrict__ W_e,
    const float* __restrict__ cb, const float* __restrict__ att,
    const float* __restrict__ att_sc, const float* __restrict__ ebias,
    float* __restrict__ lgs, unsigned short* __restrict__ msg) {
    int lane = threadIdx.x & 63, wid = threadIdx.x >> 6;
    int grp = lane >> 4, col = lane & 15;

    short8 B[8][2];
#pragma unroll
    for (int t = 0; t < 8; ++t)
#pragma unroll
        for (int kt = 0; kt < 2; ++kt)
            B[t][kt] = ldfrag(W_e + (size_t)(t * 16 + col) * ED + kt * 32 + grp * 8);

    float attv[8], cbe0[8], cbe1[8];
#pragma unroll
    for (int t = 0; t < 8; ++t) {
        int f = t * 16 + col;
        attv[t] = att[f];
        cbe0[t] = cb[f] + ebias[f * 2];
        cbe1[t] = cb[F + f] + ebias[f * 2 + 1];
    }
    float as0 = att_sc[0], as1 = att_sc[1];
    float2* lgs2 = reinterpret_cast<float2*>(lgs);

    const int NT = NE / 16;
    const int stride = gridDim.x * 4;
    int tile = blockIdx.x * 4 + wid;

    // pipeline state: current tile's metadata + raw ea floats
    int2 pe = {0, 0};
    int tgtv = 0;
    float4 rc0, rc1, rc2, rc3;
    if (tile < NT) {
        pe = perm2[tile * 16 + col];
        tgtv = tgts[tile * 16 + col];
        const float* base = ea + (size_t)pe.x * ED + grp * 8;
        const float4* ap = reinterpret_cast<const float4*>(base);
        rc0 = ap[0]; rc1 = ap[1];
        const float4* ap2 = reinterpret_cast<const float4*>(base + 32);
        rc2 = ap2[0]; rc3 = ap2[1];
    }

    for (; tile < NT; tile += stride) {
        int tn = tile + stride;
        // ---- prefetch next tile: sequential metadata, then scattered ea ----
        int2 pe_n = {0, 0};
        int tgt_n = 0;
        float4 rn0 = {}, rn1 = {}, rn2 = {}, rn3 = {};
        if (tn < NT) {
            pe_n = perm2[tn * 16 + col];
            tgt_n = tgts[tn * 16 + col];
            const float* base = ea + (size_t)pe_n.x * ED + grp * 8;
            const float4* ap = reinterpret_cast<const float4*>(base);
            rn0 = ap[0]; rn1 = ap[1];
            const float4* ap2 = reinterpret_cast<const float4*>(base + 32);
            rn2 = ap2[0]; rn3 = ap2[1];
        }

        // ---- current tile: everything already resident ----
        int p0 = tile * 16;
        int srcv = pe.y;
        // hoisted xs gathers (fly during MFMA block)
        int tgti[4];
        ushort8 xsv[4];
#pragma unroll
        for (int j = 0; j < 4; ++j) {
            int idx = grp * 4 + j;
            int src = __shfl(srcv, idx, 16);
            tgti[j] = __shfl(tgtv, idx, 16);
            xsv[j] = *reinterpret_cast<const ushort8*>(
                xbp + (size_t)src * F + col * 8);
        }

        short8 a0 = cvt8(rc0, rc1);
        short8 a1 = cvt8(rc2, rc3);
        f32x4 acc[8];
#pragma unroll
        for (int t = 0; t < 8; ++t) acc[t] = (f32x4){0.f, 0.f, 0.f, 0.f};
#pragma unroll
        for (int t = 0; t < 8; ++t) {
            acc[t] = __builtin_amdgcn_mfma_f32_16x16x32_bf16(a0, B[t][0], acc[t], 0, 0, 0);
            acc[t] = __builtin_amdgcn_mfma_f32_16x16x32_bf16(a1, B[t][1], acc[t], 0, 0, 0);
        }
#pragma unroll
        for (int j = 0; j < 4; ++j) {
            int idx = grp * 4 + j;
            ushort8 xs = xsv[j];
            ushort8 xt = *reinterpret_cast<const ushort8*>(
                xbp + (size_t)tgti[j] * F + col * 8);   // ~uniform -> L1 hit
            float q0 = 0.f, q1 = 0.f;
            ushort8 mvs;
#pragma unroll
            for (int t = 0; t < 8; ++t) {
                float mv = b2f(xs[t]) + acc[t][j];        // xj + emb
                mvs[t] = (unsigned short)bf16r(mv);
                float s = mv + b2f(xt[t]);
                float u0 = s + cbe0[t]; u0 = fmaxf(u0, NEG * u0);
                float u1 = s + cbe1[t]; u1 = fmaxf(u1, NEG * u1);
                q0 = fmaf(u0, attv[t], q0);
                q1 = fmaf(u1, attv[t], q1);
            }
            if (MODE >= 1)  // one 16B packed store
                *reinterpret_cast<ushort8*>(msg + (size_t)(p0 + idx) * F + col * 8) = mvs;
#pragma unroll
            for (int off = 8; off; off >>= 1) {
                q0 += __shfl_xor(q0, off, 16);
                q1 += __shfl_xor(q1, off, 16);
            }
            if (col == 0) {
                float2 o; o.x = q0 * as0; o.y = q1 * as1;
                lgs2[p0 + idx] = o;
            }
        }
        // ---- rotate pipeline ----
        pe = pe_n; tgtv = tgt_n;
        rc0 = rn0; rc1 = rn1; rc2 = rn2; rc3 = rn3;
    }
}

// ---------------- streaming aggregation from packed msg ----------------
// lane reads packed q = {2*lane, 2*lane+1}; f = (q&7)*16 + (q>>3)
__global__ __launch_bounds__(512) void agg_msg(
    const int* __restrict__ offs, const int2* __restrict__ perm2,
    const unsigned short* __restrict__ msg, const float* __restrict__ ebias,
    const float* __restrict__ lgs,
    float* __restrict__ out, float* __restrict__ alpha_out) {
    int lane = threadIdx.x & 63;
    int node = blockIdx.x * 8 + (threadIdx.x >> 6);
    if (node >= NN) return;
    int beg = offs[node], end = offs[node + 1];
    int deg = end - beg;
    float* orow = out + (size_t)node * (C * F);
    float2* orow2 = reinterpret_cast<float2*>(orow);
    if (deg == 0) {
        float2 z; z.x = 0.f; z.y = 0.f;
        orow2[lane] = z; orow2[64 + lane] = z;
        return;
    }
    const float2* lgs2 = reinterpret_cast<const float2*>(lgs);
    float2* al2 = reinterpret_cast<float2*>(alpha_out);

    float m0 = -FLTMAX, m1 = -FLTMAX;
    for (int j = beg + lane; j < end; j += 64) {
        float2 lg = lgs2[j];
        m0 = fmaxf(m0, lg.x); m1 = fmaxf(m1, lg.y);
    }
#pragma unroll
    for (int off = 32; off; off >>= 1) {
        m0 = fmaxf(m0, __shfl_xor(m0, off, 64));
        m1 = fmaxf(m1, __shfl_xor(m1, off, 64));
    }
    float su0 = 0.f, su1 = 0.f;
    for (int j = beg + lane; j < end; j += 64) {
        float2 lg = lgs2[j];
        su0 += __expf(lg.x - m0); su1 += __expf(lg.y - m1);
    }
#pragma unroll
    for (int off = 32; off; off >>= 1) {
        su0 += __shfl_xor(su0, off, 64);
        su1 += __shfl_xor(su1, off, 64);
    }
    float inv0 = 1.f / (su0 + 1e-16f), inv1 = 1.f / (su1 + 1e-16f);

    float g00 = 0.f, g01 = 0.f, g10 = 0.f, g11 = 0.f;
    for (int cb0 = beg; cb0 < end; cb0 += 64) {
        int cnt = min(64, end - cb0);
        int jl = cb0 + min(lane, cnt - 1);
        bool act = lane < cnt;
        int el = perm2[jl].x;
        float2 lgl = lgs2[jl];
        float e0v = act ? __expf(lgl.x - m0) : 0.f;
        float e1v = act ? __expf(lgl.y - m1) : 0.f;
        if (act) { float2 av; av.x = e0v * inv0; av.y = e1v * inv1; al2[el] = av; }
#pragma unroll 4
        for (int i = 0; i < cnt; ++i) {
            float a0 = __shfl(e0v, i, 64) * inv0;
            float a1 = __shfl(e1v, i, 64) * inv1;
            unsigned mv = *reinterpret_cast<const unsigned*>(
                msg + (size_t)(cb0 + i) * F + lane * 2);
            float f0 = __uint_as_float((mv & 0xffffu) << 16);
            float f1 = __uint_as_float(mv & 0xffff0000u);
            g00 = fmaf(a0, f0, g00); g01 = fmaf(a0, f1, g01);
            g10 = fmaf(a1, f0, g10); g11 = fmaf(a1, f1, g11);
        }
    }
    float sa0 = su0 * inv0, sa1 = su1 * inv1;
    // packed positions q0=2*lane (t even), q1=2*lane+1 -> f = (q&7)*16 + (q>>3)
    int q0i = 2 * lane;
    int f0i = (q0i & 7) * 16 + (q0i >> 3);
    int f1i = f0i + 16;                      // q1 = q0+1, t+1
    orow[f0i]       = g00 + ebias[f0i * 2] * sa0;
    orow[f1i]       = g01 + ebias[f1i * 2] * sa0;
    orow[F + f0i]   = g10 + ebias[f0i * 2 + 1] * sa1;
    orow[F + f1i]   = g11 + ebias[f1i * 2 + 1] * sa1;
}

// ---------------- fallback (never expected to run): gather agg + H + emb_gemm ----------------
__device__ __forceinline__ float xbval(const unsigned short* __restrict__ xbp,
                                       int n, int f) {
    return b2f(xbp[(size_t)n * F + (f & 15) * 8 + (f >> 4)]);
}

__global__ __launch_bounds__(512) void agg_fast(
    const int* __restrict__ offs, const int2* __restrict__ perm2,
    const float* __restrict__ ea, const unsigned short* __restrict__ xbp,
    const float* __restrict__ ebias, const float* __restrict__ lgs,
    float* __restrict__ out, float* __restrict__ alpha_out,
    float* __restrict__ H) {
    int lane = threadIdx.x & 63;
    int node = blockIdx.x * 8 + (threadIdx.x >> 6);
    if (node >= NN) return;
    int beg = offs[node], end = offs[node + 1];
    int deg = end - beg;
    float* orow = out + (size_t)node * (C * F);
    float* hrow = H + (size_t)node * (C * ED);

    if (deg == 0) {
        orow[lane] = 0.f; orow[64 + lane] = 0.f;
        orow[128 + lane] = 0.f; orow[192 + lane] = 0.f;
        if (lane < 32) { hrow[lane * 4] = 0.f; hrow[lane * 4 + 1] = 0.f;
                         hrow[lane * 4 + 2] = 0.f; hrow[lane * 4 + 3] = 0.f; }
        return;
    }
    const float2* lgs2 = reinterpret_cast<const float2*>(lgs);
    float2* al2 = reinterpret_cast<float2*>(alpha_out);

    float m0 = -FLTMAX, m1 = -FLTMAX;
    for (int j = beg + lane; j < end; j += 64) {
        float2 lg = lgs2[j];
        m0 = fmaxf(m0, lg.x); m1 = fmaxf(m1, lg.y);
    }
#pragma unroll
    for (int off = 32; off; off >>= 1) {
        m0 = fmaxf(m0, __shfl_xor(m0, off, 64));
        m1 = fmaxf(m1, __shfl_xor(m1, off, 64));
    }
    float s0 = 0.f, s1 = 0.f;
    for (int j = beg + lane; j < end; j += 64) {
        float2 lg = lgs2[j];
        s0 += __expf(lg.x - m0); s1 += __expf(lg.y - m1);
    }
#pragma unroll
    for (int off = 32; off; off >>= 1) {
        s0 += __shfl_xor(s0, off, 64);
        s1 += __shfl_xor(s1, off, 64);
    }
    float inv0 = 1.f / (s0 + 1e-16f), inv1 = 1.f / (s1 + 1e-16f);

    float h0 = 0.f, h1 = 0.f;
    float g00 = 0.f, g01 = 0.f, g10 = 0.f, g11 = 0.f;
    for (int j = beg; j < end; ++j) {
        int2 pe; pe.x = __builtin_amdgcn_readfirstlane(perm2[j].x);
        pe.y = __builtin_amdgcn_readfirstlane(perm2[j].y);
        float2 lg = lgs2[j];
        float a0 = __builtin_amdgcn_readfirstlane(__expf(lg.x - m0)) * inv0;
        float a1 = __builtin_amdgcn_readfirstlane(__expf(lg.y - m1)) * inv1;
        if (lane == 0) { float2 av; av.x = a0; av.y = a1; al2[pe.x] = av; }
        float av = ea[(size_t)pe.x * ED + lane];
        h0 = fmaf(a0, av, h0); h1 = fmaf(a1, av, h1);
        float xv0 = xbval(xbp, pe.y, lane);
        float xv1 = xbval(xbp, pe.y, 64 + lane);
        g00 = fmaf(a0, xv0, g00); g01 = fmaf(a1, xv0, g01);
        g10 = fmaf(a0, xv1, g10); g11 = fmaf(a1, xv1, g11);
    }
    hrow[lane] = h0; hrow[64 + lane] = h1;
    float sa0 = s0 * inv0, sa1 = s1 * inv1;
    orow[lane]       = g00 + ebias[lane * 2] * sa0;
    orow[64 + lane]  = g10 + ebias[(64 + lane) * 2] * sa0;
    orow[128 + lane] = g01 + ebias[lane * 2 + 1] * sa1;
    orow[192 + lane] = g11 + ebias[(64 + lane) * 2 + 1] * sa1;
}

__global__ __launch_bounds__(512) void emb_gemm(const float* __restrict__ H,
                                                const float* __restrict__ W_e,
                                                float* __restrict__ out) {
    __shared__ float WeT[ED][F];
    for (int i = threadIdx.x; i < ED * F; i += 512) {
        int f = i & (F - 1), k = i >> 7;
        WeT[k][f] = W_e[(size_t)f * ED + k];
    }
    __syncthreads();
    int lane = threadIdx.x & 63, wid = threadIdx.x >> 6;
    const int R = NN * C;
    for (int row = blockIdx.x * 8 + wid; row < R; row += gridDim.x * 8) {
        float h = H[(size_t)row * ED + lane];
        float m0 = 0.f, m1 = 0.f;
#pragma unroll
        for (int k = 0; k < ED; ++k) {
            float hk = __shfl(h, k, 64);
            m0 = fmaf(hk, WeT[k][lane], m0);
            m1 = fmaf(hk, WeT[k][lane + 64], m1);
        }
        float* op = out + (size_t)row * F;
        op[lane] += m0;
        op[lane + 64] += m1;
    }
}

extern "C" void kernel_launch(void* const* d_in, const int* in_sizes, int n_in,
                              void* d_out, int out_size, void* d_ws, size_t ws_size,
                              hipStream_t stream) {
    const float* x      = (const float*)d_in[0];
    const int*   ei     = (const int*)d_in[1];
    const float* ea     = (const float*)d_in[2];
    const float* W_l    = (const float*)d_in[3];
    const float* cb     = (const float*)d_in[4];
    const float* att    = (const float*)d_in[5];
    const float* att_sc = (const float*)d_in[6];
    const float* W_e    = (const float*)d_in[7];
    const float* ebias  = (const float*)d_in[8];

    float* out = (float*)d_out;
    float* alpha_out = out + (size_t)NN * C * F;

    float* ws = (float*)d_ws;
    unsigned short* xbp = (unsigned short*)ws;   // 12.8 MB (region reserves 25.6)
    float* lgs  = ws + 6400000;                  // 4 MB
    int* ibase  = (int*)(ws + 7400000);
    int* counts = ibase;                         // NN (becomes cursor)
    int* offs   = ibase + NN;                    // NN+1 (pad to 100064)
    int* bsum   = ibase + 100064;                // 64
    int* tgts   = ibase + 100128;                // NE
    int2* perm2 = (int2*)(ibase + 100128 + NE);  // NE int2
    char* tail = (char*)(ibase + 100128 + 3 * NE);
    tail = (char*)(((size_t)tail + 15) & ~(size_t)15);
    size_t head_bytes = (size_t)(tail - (char*)d_ws);
    size_t msg_bytes = (size_t)NE * F * 2;       // 128 MB
    bool use_msg = ws_size >= head_bytes + msg_bytes + 64;
    unsigned short* msg = (unsigned short*)tail;
    float* H = (float*)tail;

    hipMemsetAsync(counts, 0, NN * sizeof(int), stream);

    proj_hist<<<PROJ_BLOCKS + HIST_BLOCKS, 256, 0, stream>>>(x, W_l, xbp, ei, counts);

    const int NB = (NN + 1023) / 1024; // 49
    scan1_kernel<<<NB, 1024, 0, stream>>>(counts, offs, bsum);
    scan3b_kernel<<<NB, 1024, 0, stream>>>(offs, bsum, counts); // counts = cursor
    scatter_kernel<<<(NE + 255) / 256, 256, 0, stream>>>(ei, counts, perm2, tgts);

    if (use_msg) {
        edge_logits_mfma<1><<<2048, 256, 0, stream>>>(perm2, tgts, ea, xbp, W_e,
                                                      cb, att, att_sc, ebias,
                                                      lgs, msg);
        agg_msg<<<(NN + 7) / 8, 512, 0, stream>>>(offs, perm2, msg, ebias, lgs,
                                                  out, alpha_out);
    } else {
        edge_logits_mfma<0><<<2048, 256, 0, stream>>>(perm2, tgts, ea, xbp, W_e,
                                                      cb, att, att_sc, ebias,
                                                      lgs, (unsigned short*)0);
        agg_fast<<<(NN + 7) / 8, 512, 0, stream>>>(offs, perm2, ea, xbp, ebias, lgs,
                                                   out, alpha_out, H);
        emb_gemm<<<1024, 512, 0, stream>>>(H, W_e, out);
    }
}

// Round 19
// 221.794 us; speedup vs baseline: 1.1828x; 1.1386x over previous
//
#include <hip/hip_runtime.h>
#include <hip/hip_bf16.h>

#define NN 50000
#define NE 500000
#define F 128
#define K_IN 128
#define ED 64
#define C 2
#define NEG 0.2f
#define FLTMAX 3.402823466e38f
#define PROJ_BLOCKS 782
#define HIST_BLOCKS 1954

typedef __attribute__((ext_vector_type(8))) short short8;
typedef __attribute__((ext_vector_type(8))) unsigned short ushort8;
typedef __attribute__((ext_vector_type(4))) float f32x4;

__device__ __forceinline__ short bf16r(float f) {
    unsigned u = __float_as_uint(f);
    unsigned r = (u + 0x7fffu + ((u >> 16) & 1u)) >> 16;
    return (short)r;
}

__device__ __forceinline__ float b2f(unsigned short v) {
    return __uint_as_float(((unsigned)v) << 16);
}

__device__ __forceinline__ short8 ldfrag(const float* base) {
    const float4* p = reinterpret_cast<const float4*>(base);
    float4 v0 = p[0], v1 = p[1];
    short8 r;
    r[0] = bf16r(v0.x); r[1] = bf16r(v0.y); r[2] = bf16r(v0.z); r[3] = bf16r(v0.w);
    r[4] = bf16r(v1.x); r[5] = bf16r(v1.y); r[6] = bf16r(v1.z); r[7] = bf16r(v1.w);
    return r;
}

__device__ __forceinline__ short8 cvt8(float4 v0, float4 v1) {
    short8 r;
    r[0] = bf16r(v0.x); r[1] = bf16r(v0.y); r[2] = bf16r(v0.z); r[3] = bf16r(v0.w);
    r[4] = bf16r(v1.x); r[5] = bf16r(v1.y); r[6] = bf16r(v1.z); r[7] = bf16r(v1.w);
    return r;
}

// packed xb layout: xbp[n*128 + col*8 + t] = bf16(x_base[n][t*16+col])
// ---------------- fused: proj (blocks < PROJ_BLOCKS) + hist (rest) ----------------
__global__ __launch_bounds__(256) void proj_hist(const float* __restrict__ x,
                                                 const float* __restrict__ W_l,
                                                 unsigned short* __restrict__ xbp,
                                                 const int* __restrict__ ei,
                                                 int* __restrict__ counts) {
    if (blockIdx.x < PROJ_BLOCKS) {
        int lane = threadIdx.x & 63, wid = threadIdx.x >> 6;
        int grp = lane >> 4, col = lane & 15;
        int tile = blockIdx.x * 4 + wid;
        if (tile >= NN / 16) return;
        int n0 = tile * 16;

        f32x4 acc[8];
#pragma unroll
        for (int t = 0; t < 8; ++t) acc[t] = (f32x4){0.f, 0.f, 0.f, 0.f};

        const float* arow = x + (size_t)(n0 + col) * K_IN + grp * 8;
#pragma unroll
        for (int kt = 0; kt < 4; ++kt) {
            short8 a = ldfrag(arow + kt * 32);
#pragma unroll
            for (int t = 0; t < 8; ++t) {
                short8 b = ldfrag(W_l + (size_t)(t * 16 + col) * K_IN + kt * 32 + grp * 8);
                acc[t] = __builtin_amdgcn_mfma_f32_16x16x32_bf16(a, b, acc[t], 0, 0, 0);
            }
        }
#pragma unroll
        for (int j = 0; j < 4; ++j) {
            ushort8 o;
#pragma unroll
            for (int t = 0; t < 8; ++t) o[t] = (unsigned short)bf16r(acc[t][j]);
            *reinterpret_cast<ushort8*>(xbp + (size_t)(n0 + grp * 4 + j) * F + col * 8) = o;
        }
    } else {
        int e = (blockIdx.x - PROJ_BLOCKS) * 256 + threadIdx.x;
        if (e < NE) atomicAdd(&counts[ei[NE + e]], 1);
    }
}

// ---------------- CSR build ----------------
__global__ __launch_bounds__(1024) void scan1_kernel(const int* __restrict__ counts,
                                                     int* __restrict__ offs,
                                                     int* __restrict__ bsum) {
    __shared__ int wsum[16];
    int i = blockIdx.x * 1024 + threadIdx.x;
    int lane = threadIdx.x & 63, w = threadIdx.x >> 6;
    int v = (i < NN) ? counts[i] : 0;
    int x = v;
#pragma unroll
    for (int off = 1; off < 64; off <<= 1) {
        int y = __shfl_up(x, off, 64);
        if (lane >= off) x += y;
    }
    if (lane == 63) wsum[w] = x;
    __syncthreads();
    if (w == 0 && lane < 16) {
        int t = wsum[lane];
#pragma unroll
        for (int off = 1; off < 16; off <<= 1) {
            int y = __shfl_up(t, off, 16);
            if (lane >= off) t += y;
        }
        wsum[lane] = t;
    }
    __syncthreads();
    int woff = (w == 0) ? 0 : wsum[w - 1];
    if (i < NN) offs[i] = woff + x - v;
    if (threadIdx.x == 1023) bsum[blockIdx.x] = woff + x;
}

// scan3b: each block derives its own carry from bsum (<=64 entries)
__global__ __launch_bounds__(1024) void scan3b_kernel(int* __restrict__ offs,
                                                      const int* __restrict__ bsum,
                                                      int* __restrict__ cursor) {
    __shared__ int carry_s;
    if (threadIdx.x < 64) {
        int v = (threadIdx.x < blockIdx.x) ? bsum[threadIdx.x] : 0;
#pragma unroll
        for (int off = 32; off; off >>= 1) v += __shfl_xor(v, off, 64);
        if (threadIdx.x == 0) carry_s = v;
    }
    __syncthreads();
    int carry = carry_s;
    int i = blockIdx.x * 1024 + threadIdx.x;
    if (i < NN) {
        int o = offs[i] + carry;
        offs[i] = o;
        cursor[i] = o;
    }
    if (blockIdx.x == 0 && threadIdx.x == 0) offs[NN] = NE;
}

// perm2[p] = {edge, src}; tgts[p] = tgt
__global__ void scatter_kernel(const int* __restrict__ ei, int* __restrict__ cursor,
                               int2* __restrict__ perm2, int* __restrict__ tgts) {
    int e = blockIdx.x * blockDim.x + threadIdx.x;
    if (e < NE) {
        int src = ei[e];
        int tgt = ei[NE + e];
        int p = atomicAdd(&cursor[tgt], 1);
        int2 v; v.x = e; v.y = src;
        perm2[p] = v;
        tgts[p] = tgt;
    }
}

// ---------------- edge logits: issue-ordered pipeline ----------------
// per iteration: [xs/xt gathers (oldest)] -> [ea_next] -> [meta t+2] ->
// MFMA (B from LDS) -> load-free j-loop. Consuming xs/xt drains only the
// 8 oldest loads; ea_next stays in flight across the body + backedge.
// msg packed layout: msg[p*F + col*8 + t] = bf16(xj+emb at f=t*16+col)
template<int MODE>
__global__ __launch_bounds__(256) void edge_logits_mfma(
    const int2* __restrict__ perm2, const int* __restrict__ tgts,
    const float* __restrict__ ea,
    const unsigned short* __restrict__ xbp, const float* __restrict__ W_e,
    const float* __restrict__ cb, const float* __restrict__ att,
    const float* __restrict__ att_sc, const float* __restrict__ ebias,
    float* __restrict__ lgs, unsigned short* __restrict__ msg) {
    __shared__ short8 Blds[16][64];   // W_e fragments, 16 KB, conflict-free reads
    int lane = threadIdx.x & 63, wid = threadIdx.x >> 6;
    int grp = lane >> 4, col = lane & 15;

    for (int fidx = threadIdx.x; fidx < 1024; fidx += 256) {
        int l = fidx & 63, kt = (fidx >> 6) & 1, t = fidx >> 7;
        int g2 = l >> 4, c2 = l & 15;
        Blds[t * 2 + kt][l] = ldfrag(W_e + (size_t)(t * 16 + c2) * ED + kt * 32 + g2 * 8);
    }

    float attv[8], cbe0[8], cbe1[8];
#pragma unroll
    for (int t = 0; t < 8; ++t) {
        int f = t * 16 + col;
        attv[t] = att[f];
        cbe0[t] = cb[f] + ebias[f * 2];
        cbe1[t] = cb[F + f] + ebias[f * 2 + 1];
    }
    float as0 = att_sc[0], as1 = att_sc[1];
    float2* lgs2 = reinterpret_cast<float2*>(lgs);
    __syncthreads();

    const int NT = NE / 16;
    const int stride = gridDim.x * 4;
    int tile = blockIdx.x * 4 + wid;

    // pipeline state: current metadata, next metadata, current raw ea
    int2 pe = {0, 0}, pe_n = {0, 0};
    int tgtv = 0, tgt_n = 0;
    float4 rc0, rc1, rc2, rc3;
    if (tile < NT) {
        pe = perm2[tile * 16 + col];
        tgtv = tgts[tile * 16 + col];
    }
    {
        int tb = tile + stride;
        if (tb < NT) {
            pe_n = perm2[tb * 16 + col];
            tgt_n = tgts[tb * 16 + col];
        }
    }
    if (tile < NT) {
        const float* base = ea + (size_t)pe.x * ED + grp * 8;
        const float4* ap = reinterpret_cast<const float4*>(base);
        rc0 = ap[0]; rc1 = ap[1];
        const float4* ap2 = reinterpret_cast<const float4*>(base + 32);
        rc2 = ap2[0]; rc3 = ap2[1];
    }

    for (; tile < NT; tile += stride) {
        int tn = tile + stride;
        int tnn = tile + 2 * stride;
        int p0 = tile * 16;
        int srcv = pe.y;

        // (a) OLDEST: current-tile xs + xt gathers (metadata resident)
        int tgti[4];
        ushort8 xsv[4], xtv[4];
#pragma unroll
        for (int j = 0; j < 4; ++j) {
            int idx = grp * 4 + j;
            int src = __shfl(srcv, idx, 16);
            tgti[j] = __shfl(tgtv, idx, 16);
            xsv[j] = *reinterpret_cast<const ushort8*>(
                xbp + (size_t)src * F + col * 8);
            xtv[j] = *reinterpret_cast<const ushort8*>(
                xbp + (size_t)tgti[j] * F + col * 8);
        }
        // (b) ea for NEXT tile (pe_n resident -> no wait before issue)
        float4 rn0 = {}, rn1 = {}, rn2 = {}, rn3 = {};
        if (tn < NT) {
            const float* base = ea + (size_t)pe_n.x * ED + grp * 8;
            const float4* ap = reinterpret_cast<const float4*>(base);
            rn0 = ap[0]; rn1 = ap[1];
            const float4* ap2 = reinterpret_cast<const float4*>(base + 32);
            rn2 = ap2[0]; rn3 = ap2[1];
        }
        // (c) metadata two ahead (sequential)
        int2 pe_nn = {0, 0};
        int tgt_nn = 0;
        if (tnn < NT) {
            pe_nn = perm2[tnn * 16 + col];
            tgt_nn = tgts[tnn * 16 + col];
        }

        // (d) compute: current ea already in registers; B from LDS
        short8 a0 = cvt8(rc0, rc1);
        short8 a1 = cvt8(rc2, rc3);
        f32x4 acc[8];
#pragma unroll
        for (int t = 0; t < 8; ++t) acc[t] = (f32x4){0.f, 0.f, 0.f, 0.f};
#pragma unroll
        for (int t = 0; t < 8; ++t) {
            acc[t] = __builtin_amdgcn_mfma_f32_16x16x32_bf16(a0, Blds[t * 2][lane], acc[t], 0, 0, 0);
            acc[t] = __builtin_amdgcn_mfma_f32_16x16x32_bf16(a1, Blds[t * 2 + 1][lane], acc[t], 0, 0, 0);
        }
        // (e) load-free j-loop
#pragma unroll
        for (int j = 0; j < 4; ++j) {
            int idx = grp * 4 + j;
            ushort8 xs = xsv[j];
            ushort8 xt = xtv[j];
            float q0 = 0.f, q1 = 0.f;
            ushort8 mvs;
#pragma unroll
            for (int t = 0; t < 8; ++t) {
                float mv = b2f(xs[t]) + acc[t][j];        // xj + emb
                mvs[t] = (unsigned short)bf16r(mv);
                float s = mv + b2f(xt[t]);
                float u0 = s + cbe0[t]; u0 = fmaxf(u0, NEG * u0);
                float u1 = s + cbe1[t]; u1 = fmaxf(u1, NEG * u1);
                q0 = fmaf(u0, attv[t], q0);
                q1 = fmaf(u1, attv[t], q1);
            }
            if (MODE >= 1)
                *reinterpret_cast<ushort8*>(msg + (size_t)(p0 + idx) * F + col * 8) = mvs;
#pragma unroll
            for (int off = 8; off; off >>= 1) {
                q0 += __shfl_xor(q0, off, 16);
                q1 += __shfl_xor(q1, off, 16);
            }
            if (col == 0) {
                float2 o; o.x = q0 * as0; o.y = q1 * as1;
                lgs2[p0 + idx] = o;
            }
        }
        // (f) rotate
        pe = pe_n; tgtv = tgt_n;
        pe_n = pe_nn; tgt_n = tgt_nn;
        rc0 = rn0; rc1 = rn1; rc2 = rn2; rc3 = rn3;
    }
}

// ---------------- streaming aggregation from packed msg ----------------
// lane reads packed q = {2*lane, 2*lane+1}; f = (q&7)*16 + (q>>3)
__global__ __launch_bounds__(512) void agg_msg(
    const int* __restrict__ offs, const int2* __restrict__ perm2,
    const unsigned short* __restrict__ msg, const float* __restrict__ ebias,
    const float* __restrict__ lgs,
    float* __restrict__ out, float* __restrict__ alpha_out) {
    int lane = threadIdx.x & 63;
    int node = blockIdx.x * 8 + (threadIdx.x >> 6);
    if (node >= NN) return;
    int beg = offs[node], end = offs[node + 1];
    int deg = end - beg;
    float* orow = out + (size_t)node * (C * F);
    float2* orow2 = reinterpret_cast<float2*>(orow);
    if (deg == 0) {
        float2 z; z.x = 0.f; z.y = 0.f;
        orow2[lane] = z; orow2[64 + lane] = z;
        return;
    }
    const float2* lgs2 = reinterpret_cast<const float2*>(lgs);
    float2* al2 = reinterpret_cast<float2*>(alpha_out);

    float m0 = -FLTMAX, m1 = -FLTMAX;
    for (int j = beg + lane; j < end; j += 64) {
        float2 lg = lgs2[j];
        m0 = fmaxf(m0, lg.x); m1 = fmaxf(m1, lg.y);
    }
#pragma unroll
    for (int off = 32; off; off >>= 1) {
        m0 = fmaxf(m0, __shfl_xor(m0, off, 64));
        m1 = fmaxf(m1, __shfl_xor(m1, off, 64));
    }
    float su0 = 0.f, su1 = 0.f;
    for (int j = beg + lane; j < end; j += 64) {
        float2 lg = lgs2[j];
        su0 += __expf(lg.x - m0); su1 += __expf(lg.y - m1);
    }
#pragma unroll
    for (int off = 32; off; off >>= 1) {
        su0 += __shfl_xor(su0, off, 64);
        su1 += __shfl_xor(su1, off, 64);
    }
    float inv0 = 1.f / (su0 + 1e-16f), inv1 = 1.f / (su1 + 1e-16f);

    float g00 = 0.f, g01 = 0.f, g10 = 0.f, g11 = 0.f;
    for (int cb0 = beg; cb0 < end; cb0 += 64) {
        int cnt = min(64, end - cb0);
        int jl = cb0 + min(lane, cnt - 1);
        bool act = lane < cnt;
        int el = perm2[jl].x;
        float2 lgl = lgs2[jl];
        float e0v = act ? __expf(lgl.x - m0) : 0.f;
        float e1v = act ? __expf(lgl.y - m1) : 0.f;
        if (act) { float2 av; av.x = e0v * inv0; av.y = e1v * inv1; al2[el] = av; }
#pragma unroll 4
        for (int i = 0; i < cnt; ++i) {
            float a0 = __shfl(e0v, i, 64) * inv0;
            float a1 = __shfl(e1v, i, 64) * inv1;
            unsigned mv = *reinterpret_cast<const unsigned*>(
                msg + (size_t)(cb0 + i) * F + lane * 2);
            float f0 = __uint_as_float((mv & 0xffffu) << 16);
            float f1 = __uint_as_float(mv & 0xffff0000u);
            g00 = fmaf(a0, f0, g00); g01 = fmaf(a0, f1, g01);
            g10 = fmaf(a1, f0, g10); g11 = fmaf(a1, f1, g11);
        }
    }
    float sa0 = su0 * inv0, sa1 = su1 * inv1;
    // packed positions q0=2*lane (t even), q1=2*lane+1 -> f = (q&7)*16 + (q>>3)
    int q0i = 2 * lane;
    int f0i = (q0i & 7) * 16 + (q0i >> 3);
    int f1i = f0i + 16;                      // q1 = q0+1, t+1
    orow[f0i]       = g00 + ebias[f0i * 2] * sa0;
    orow[f1i]       = g01 + ebias[f1i * 2] * sa0;
    orow[F + f0i]   = g10 + ebias[f0i * 2 + 1] * sa1;
    orow[F + f1i]   = g11 + ebias[f1i * 2 + 1] * sa1;
}

// ---------------- fallback (never expected to run): gather agg + H + emb_gemm ----------------
__device__ __forceinline__ float xbval(const unsigned short* __restrict__ xbp,
                                       int n, int f) {
    return b2f(xbp[(size_t)n * F + (f & 15) * 8 + (f >> 4)]);
}

__global__ __launch_bounds__(512) void agg_fast(
    const int* __restrict__ offs, const int2* __restrict__ perm2,
    const float* __restrict__ ea, const unsigned short* __restrict__ xbp,
    const float* __restrict__ ebias, const float* __restrict__ lgs,
    float* __restrict__ out, float* __restrict__ alpha_out,
    float* __restrict__ H) {
    int lane = threadIdx.x & 63;
    int node = blockIdx.x * 8 + (threadIdx.x >> 6);
    if (node >= NN) return;
    int beg = offs[node], end = offs[node + 1];
    int deg = end - beg;
    float* orow = out + (size_t)node * (C * F);
    float* hrow = H + (size_t)node * (C * ED);

    if (deg == 0) {
        orow[lane] = 0.f; orow[64 + lane] = 0.f;
        orow[128 + lane] = 0.f; orow[192 + lane] = 0.f;
        if (lane < 32) { hrow[lane * 4] = 0.f; hrow[lane * 4 + 1] = 0.f;
                         hrow[lane * 4 + 2] = 0.f; hrow[lane * 4 + 3] = 0.f; }
        return;
    }
    const float2* lgs2 = reinterpret_cast<const float2*>(lgs);
    float2* al2 = reinterpret_cast<float2*>(alpha_out);

    float m0 = -FLTMAX, m1 = -FLTMAX;
    for (int j = beg + lane; j < end; j += 64) {
        float2 lg = lgs2[j];
        m0 = fmaxf(m0, lg.x); m1 = fmaxf(m1, lg.y);
    }
#pragma unroll
    for (int off = 32; off; off >>= 1) {
        m0 = fmaxf(m0, __shfl_xor(m0, off, 64));
        m1 = fmaxf(m1, __shfl_xor(m1, off, 64));
    }
    float s0 = 0.f, s1 = 0.f;
    for (int j = beg + lane; j < end; j += 64) {
        float2 lg = lgs2[j];
        s0 += __expf(lg.x - m0); s1 += __expf(lg.y - m1);
    }
#pragma unroll
    for (int off = 32; off; off >>= 1) {
        s0 += __shfl_xor(s0, off, 64);
        s1 += __shfl_xor(s1, off, 64);
    }
    float inv0 = 1.f / (s0 + 1e-16f), inv1 = 1.f / (s1 + 1e-16f);

    float h0 = 0.f, h1 = 0.f;
    float g00 = 0.f, g01 = 0.f, g10 = 0.f, g11 = 0.f;
    for (int j = beg; j < end; ++j) {
        int2 pe; pe.x = __builtin_amdgcn_readfirstlane(perm2[j].x);
        pe.y = __builtin_amdgcn_readfirstlane(perm2[j].y);
        float2 lg = lgs2[j];
        float a0 = __builtin_amdgcn_readfirstlane(__expf(lg.x - m0)) * inv0;
        float a1 = __builtin_amdgcn_readfirstlane(__expf(lg.y - m1)) * inv1;
        if (lane == 0) { float2 av; av.x = a0; av.y = a1; al2[pe.x] = av; }
        float av = ea[(size_t)pe.x * ED + lane];
        h0 = fmaf(a0, av, h0); h1 = fmaf(a1, av, h1);
        float xv0 = xbval(xbp, pe.y, lane);
        float xv1 = xbval(xbp, pe.y, 64 + lane);
        g00 = fmaf(a0, xv0, g00); g01 = fmaf(a1, xv0, g01);
        g10 = fmaf(a0, xv1, g10); g11 = fmaf(a1, xv1, g11);
    }
    hrow[lane] = h0; hrow[64 + lane] = h1;
    float sa0 = s0 * inv0, sa1 = s1 * inv1;
    orow[lane]       = g00 + ebias[lane * 2] * sa0;
    orow[64 + lane]  = g10 + ebias[(64 + lane) * 2] * sa0;
    orow[128 + lane] = g01 + ebias[lane * 2 + 1] * sa1;
    orow[192 + lane] = g11 + ebias[(64 + lane) * 2 + 1] * sa1;
}

__global__ __launch_bounds__(512) void emb_gemm(const float* __restrict__ H,
                                                const float* __restrict__ W_e,
                                                float* __restrict__ out) {
    __shared__ float WeT[ED][F];
    for (int i = threadIdx.x; i < ED * F; i += 512) {
        int f = i & (F - 1), k = i >> 7;
        WeT[k][f] = W_e[(size_t)f * ED + k];
    }
    __syncthreads();
    int lane = threadIdx.x & 63, wid = threadIdx.x >> 6;
    const int R = NN * C;
    for (int row = blockIdx.x * 8 + wid; row < R; row += gridDim.x * 8) {
        float h = H[(size_t)row * ED + lane];
        float m0 = 0.f, m1 = 0.f;
#pragma unroll
        for (int k = 0; k < ED; ++k) {
            float hk = __shfl(h, k, 64);
            m0 = fmaf(hk, WeT[k][lane], m0);
            m1 = fmaf(hk, WeT[k][lane + 64], m1);
        }
        float* op = out + (size_t)row * F;
        op[lane] += m0;
        op[lane + 64] += m1;
    }
}

extern "C" void kernel_launch(void* const* d_in, const int* in_sizes, int n_in,
                              void* d_out, int out_size, void* d_ws, size_t ws_size,
                              hipStream_t stream) {
    const float* x      = (const float*)d_in[0];
    const int*   ei     = (const int*)d_in[1];
    const float* ea     = (const float*)d_in[2];
    const float* W_l    = (const float*)d_in[3];
    const float* cb     = (const float*)d_in[4];
    const float* att    = (const float*)d_in[5];
    const float* att_sc = (const float*)d_in[6];
    const float* W_e    = (const float*)d_in[7];
    const float* ebias  = (const float*)d_in[8];

    float* out = (float*)d_out;
    float* alpha_out = out + (size_t)NN * C * F;

    float* ws = (float*)d_ws;
    unsigned short* xbp = (unsigned short*)ws;   // 12.8 MB (region reserves 25.6)
    float* lgs  = ws + 6400000;                  // 4 MB
    int* ibase  = (int*)(ws + 7400000);
    int* counts = ibase;                         // NN (becomes cursor)
    int* offs   = ibase + NN;                    // NN+1 (pad to 100064)
    int* bsum   = ibase + 100064;                // 64
    int* tgts   = ibase + 100128;                // NE
    int2* perm2 = (int2*)(ibase + 100128 + NE);  // NE int2
    char* tail = (char*)(ibase + 100128 + 3 * NE);
    tail = (char*)(((size_t)tail + 15) & ~(size_t)15);
    size_t head_bytes = (size_t)(tail - (char*)d_ws);
    size_t msg_bytes = (size_t)NE * F * 2;       // 128 MB
    bool use_msg = ws_size >= head_bytes + msg_bytes + 64;
    unsigned short* msg = (unsigned short*)tail;
    float* H = (float*)tail;

    hipMemsetAsync(counts, 0, NN * sizeof(int), stream);

    proj_hist<<<PROJ_BLOCKS + HIST_BLOCKS, 256, 0, stream>>>(x, W_l, xbp, ei, counts);

    const int NB = (NN + 1023) / 1024; // 49
    scan1_kernel<<<NB, 1024, 0, stream>>>(counts, offs, bsum);
    scan3b_kernel<<<NB, 1024, 0, stream>>>(offs, bsum, counts); // counts = cursor
    scatter_kernel<<<(NE + 255) / 256, 256, 0, stream>>>(ei, counts, perm2, tgts);

    if (use_msg) {
        edge_logits_mfma<1><<<2048, 256, 0, stream>>>(perm2, tgts, ea, xbp, W_e,
                                                      cb, att, att_sc, ebias,
                                                      lgs, msg);
        agg_msg<<<(NN + 7) / 8, 512, 0, stream>>>(offs, perm2, msg, ebias, lgs,
                                                  out, alpha_out);
    } else {
        edge_logits_mfma<0><<<2048, 256, 0, stream>>>(perm2, tgts, ea, xbp, W_e,
                                                      cb, att, att_sc, ebias,
                                                      lgs, (unsigned short*)0);
        agg_fast<<<(NN + 7) / 8, 512, 0, stream>>>(offs, perm2, ea, xbp, ebias, lgs,
                                                   out, alpha_out, H);
        emb_gemm<<<1024, 512, 0, stream>>>(H, W_e, out);
    }
}

// Round 21
// 220.465 us; speedup vs baseline: 1.1900x; 1.0060x over previous
//
#include <hip/hip_runtime.h>
#include <hip/hip_bf16.h>

#define NN 50000
#define NE 500000
#define F 128
#define K_IN 128
#define ED 64
#define C 2
#define NEG 0.2f
#define FLTMAX 3.402823466e38f
#define PROJ_BLOCKS 782
#define HIST_BLOCKS 1954

typedef __attribute__((ext_vector_type(8))) short short8;
typedef __attribute__((ext_vector_type(8))) unsigned short ushort8;
typedef __attribute__((ext_vector_type(4))) float f32x4;

__device__ __forceinline__ short bf16r(float f) {
    unsigned u = __float_as_uint(f);
    unsigned r = (u + 0x7fffu + ((u >> 16) & 1u)) >> 16;
    return (short)r;
}

__device__ __forceinline__ float b2f(unsigned short v) {
    return __uint_as_float(((unsigned)v) << 16);
}

__device__ __forceinline__ short8 ldfrag(const float* base) {
    const float4* p = reinterpret_cast<const float4*>(base);
    float4 v0 = p[0], v1 = p[1];
    short8 r;
    r[0] = bf16r(v0.x); r[1] = bf16r(v0.y); r[2] = bf16r(v0.z); r[3] = bf16r(v0.w);
    r[4] = bf16r(v1.x); r[5] = bf16r(v1.y); r[6] = bf16r(v1.z); r[7] = bf16r(v1.w);
    return r;
}

__device__ __forceinline__ short8 cvt8(float4 v0, float4 v1) {
    short8 r;
    r[0] = bf16r(v0.x); r[1] = bf16r(v0.y); r[2] = bf16r(v0.z); r[3] = bf16r(v0.w);
    r[4] = bf16r(v1.x); r[5] = bf16r(v1.y); r[6] = bf16r(v1.z); r[7] = bf16r(v1.w);
    return r;
}

// packed xb layout: xbp[n*128 + col*8 + t] = bf16(x_base[n][t*16+col])
// ---------------- fused: proj (blocks < PROJ_BLOCKS) + hist (rest) ----------------
__global__ __launch_bounds__(256) void proj_hist(const float* __restrict__ x,
                                                 const float* __restrict__ W_l,
                                                 unsigned short* __restrict__ xbp,
                                                 const int* __restrict__ ei,
                                                 int* __restrict__ counts) {
    if (blockIdx.x < PROJ_BLOCKS) {
        int lane = threadIdx.x & 63, wid = threadIdx.x >> 6;
        int grp = lane >> 4, col = lane & 15;
        int tile = blockIdx.x * 4 + wid;
        if (tile >= NN / 16) return;
        int n0 = tile * 16;

        f32x4 acc[8];
#pragma unroll
        for (int t = 0; t < 8; ++t) acc[t] = (f32x4){0.f, 0.f, 0.f, 0.f};

        const float* arow = x + (size_t)(n0 + col) * K_IN + grp * 8;
#pragma unroll
        for (int kt = 0; kt < 4; ++kt) {
            short8 a = ldfrag(arow + kt * 32);
#pragma unroll
            for (int t = 0; t < 8; ++t) {
                short8 b = ldfrag(W_l + (size_t)(t * 16 + col) * K_IN + kt * 32 + grp * 8);
                acc[t] = __builtin_amdgcn_mfma_f32_16x16x32_bf16(a, b, acc[t], 0, 0, 0);
            }
        }
#pragma unroll
        for (int j = 0; j < 4; ++j) {
            ushort8 o;
#pragma unroll
            for (int t = 0; t < 8; ++t) o[t] = (unsigned short)bf16r(acc[t][j]);
            *reinterpret_cast<ushort8*>(xbp + (size_t)(n0 + grp * 4 + j) * F + col * 8) = o;
        }
    } else {
        int e = (blockIdx.x - PROJ_BLOCKS) * 256 + threadIdx.x;
        if (e < NE) atomicAdd(&counts[ei[NE + e]], 1);
    }
}

// ---------------- CSR build ----------------
__global__ __launch_bounds__(1024) void scan1_kernel(const int* __restrict__ counts,
                                                     int* __restrict__ offs,
                                                     int* __restrict__ bsum) {
    __shared__ int wsum[16];
    int i = blockIdx.x * 1024 + threadIdx.x;
    int lane = threadIdx.x & 63, w = threadIdx.x >> 6;
    int v = (i < NN) ? counts[i] : 0;
    int x = v;
#pragma unroll
    for (int off = 1; off < 64; off <<= 1) {
        int y = __shfl_up(x, off, 64);
        if (lane >= off) x += y;
    }
    if (lane == 63) wsum[w] = x;
    __syncthreads();
    if (w == 0 && lane < 16) {
        int t = wsum[lane];
#pragma unroll
        for (int off = 1; off < 16; off <<= 1) {
            int y = __shfl_up(t, off, 16);
            if (lane >= off) t += y;
        }
        wsum[lane] = t;
    }
    __syncthreads();
    int woff = (w == 0) ? 0 : wsum[w - 1];
    if (i < NN) offs[i] = woff + x - v;
    if (threadIdx.x == 1023) bsum[blockIdx.x] = woff + x;
}

// scan3b: each block derives its own carry from bsum (<=64 entries)
__global__ __launch_bounds__(1024) void scan3b_kernel(int* __restrict__ offs,
                                                      const int* __restrict__ bsum,
                                                      int* __restrict__ cursor) {
    __shared__ int carry_s;
    if (threadIdx.x < 64) {
        int v = (threadIdx.x < blockIdx.x) ? bsum[threadIdx.x] : 0;
#pragma unroll
        for (int off = 32; off; off >>= 1) v += __shfl_xor(v, off, 64);
        if (threadIdx.x == 0) carry_s = v;
    }
    __syncthreads();
    int carry = carry_s;
    int i = blockIdx.x * 1024 + threadIdx.x;
    if (i < NN) {
        int o = offs[i] + carry;
        offs[i] = o;
        cursor[i] = o;
    }
    if (blockIdx.x == 0 && threadIdx.x == 0) offs[NN] = NE;
}

// perm2[p] = {edge, src}; tgts[p] = tgt
__global__ void scatter_kernel(const int* __restrict__ ei, int* __restrict__ cursor,
                               int2* __restrict__ perm2, int* __restrict__ tgts) {
    int e = blockIdx.x * blockDim.x + threadIdx.x;
    if (e < NE) {
        int src = ei[e];
        int tgt = ei[NE + e];
        int p = atomicAdd(&cursor[tgt], 1);
        int2 v; v.x = e; v.y = src;
        perm2[p] = v;
        tgts[p] = tgt;
    }
}

// ---------------- edge logits: issue-ordered pipeline (r19) ----------------
// per iteration: [xs/xt gathers (oldest)] -> [ea_next] -> [meta t+2] ->
// MFMA (B from LDS) -> load-free j-loop. Consuming xs/xt drains only the
// 8 oldest loads; ea_next stays in flight across the body + backedge.
// msg packed layout: msg[p*F + col*8 + t] = bf16(xj+emb at f=t*16+col)
template<int MODE>
__global__ __launch_bounds__(256) void edge_logits_mfma(
    const int2* __restrict__ perm2, const int* __restrict__ tgts,
    const float* __restrict__ ea,
    const unsigned short* __restrict__ xbp, const float* __restrict__ W_e,
    const float* __restrict__ cb, const float* __restrict__ att,
    const float* __restrict__ att_sc, const float* __restrict__ ebias,
    float* __restrict__ lgs, unsigned short* __restrict__ msg) {
    __shared__ short8 Blds[16][64];   // W_e fragments, 16 KB, conflict-free reads
    int lane = threadIdx.x & 63, wid = threadIdx.x >> 6;
    int grp = lane >> 4, col = lane & 15;

    for (int fidx = threadIdx.x; fidx < 1024; fidx += 256) {
        int l = fidx & 63, kt = (fidx >> 6) & 1, t = fidx >> 7;
        int g2 = l >> 4, c2 = l & 15;
        Blds[t * 2 + kt][l] = ldfrag(W_e + (size_t)(t * 16 + c2) * ED + kt * 32 + g2 * 8);
    }

    float attv[8], cbe0[8], cbe1[8];
#pragma unroll
    for (int t = 0; t < 8; ++t) {
        int f = t * 16 + col;
        attv[t] = att[f];
        cbe0[t] = cb[f] + ebias[f * 2];
        cbe1[t] = cb[F + f] + ebias[f * 2 + 1];
    }
    float as0 = att_sc[0], as1 = att_sc[1];
    float2* lgs2 = reinterpret_cast<float2*>(lgs);
    __syncthreads();

    const int NT = NE / 16;
    const int stride = gridDim.x * 4;
    int tile = blockIdx.x * 4 + wid;

    // pipeline state: current metadata, next metadata, current raw ea
    int2 pe = {0, 0}, pe_n = {0, 0};
    int tgtv = 0, tgt_n = 0;
    float4 rc0, rc1, rc2, rc3;
    if (tile < NT) {
        pe = perm2[tile * 16 + col];
        tgtv = tgts[tile * 16 + col];
    }
    {
        int tb = tile + stride;
        if (tb < NT) {
            pe_n = perm2[tb * 16 + col];
            tgt_n = tgts[tb * 16 + col];
        }
    }
    if (tile < NT) {
        const float* base = ea + (size_t)pe.x * ED + grp * 8;
        const float4* ap = reinterpret_cast<const float4*>(base);
        rc0 = ap[0]; rc1 = ap[1];
        const float4* ap2 = reinterpret_cast<const float4*>(base + 32);
        rc2 = ap2[0]; rc3 = ap2[1];
    }

    for (; tile < NT; tile += stride) {
        int tn = tile + stride;
        int tnn = tile + 2 * stride;
        int p0 = tile * 16;
        int srcv = pe.y;

        // (a) OLDEST: current-tile xs + xt gathers (metadata resident)
        int tgti[4];
        ushort8 xsv[4], xtv[4];
#pragma unroll
        for (int j = 0; j < 4; ++j) {
            int idx = grp * 4 + j;
            int src = __shfl(srcv, idx, 16);
            tgti[j] = __shfl(tgtv, idx, 16);
            xsv[j] = *reinterpret_cast<const ushort8*>(
                xbp + (size_t)src * F + col * 8);
            xtv[j] = *reinterpret_cast<const ushort8*>(
                xbp + (size_t)tgti[j] * F + col * 8);
        }
        // (b) ea for NEXT tile (pe_n resident -> no wait before issue)
        float4 rn0 = {}, rn1 = {}, rn2 = {}, rn3 = {};
        if (tn < NT) {
            const float* base = ea + (size_t)pe_n.x * ED + grp * 8;
            const float4* ap = reinterpret_cast<const float4*>(base);
            rn0 = ap[0]; rn1 = ap[1];
            const float4* ap2 = reinterpret_cast<const float4*>(base + 32);
            rn2 = ap2[0]; rn3 = ap2[1];
        }
        // (c) metadata two ahead (sequential)
        int2 pe_nn = {0, 0};
        int tgt_nn = 0;
        if (tnn < NT) {
            pe_nn = perm2[tnn * 16 + col];
            tgt_nn = tgts[tnn * 16 + col];
        }

        // (d) compute: current ea already in registers; B from LDS
        short8 a0 = cvt8(rc0, rc1);
        short8 a1 = cvt8(rc2, rc3);
        f32x4 acc[8];
#pragma unroll
        for (int t = 0; t < 8; ++t) acc[t] = (f32x4){0.f, 0.f, 0.f, 0.f};
#pragma unroll
        for (int t = 0; t < 8; ++t) {
            acc[t] = __builtin_amdgcn_mfma_f32_16x16x32_bf16(a0, Blds[t * 2][lane], acc[t], 0, 0, 0);
            acc[t] = __builtin_amdgcn_mfma_f32_16x16x32_bf16(a1, Blds[t * 2 + 1][lane], acc[t], 0, 0, 0);
        }
        // (e) load-free j-loop
#pragma unroll
        for (int j = 0; j < 4; ++j) {
            int idx = grp * 4 + j;
            ushort8 xs = xsv[j];
            ushort8 xt = xtv[j];
            float q0 = 0.f, q1 = 0.f;
            ushort8 mvs;
#pragma unroll
            for (int t = 0; t < 8; ++t) {
                float mv = b2f(xs[t]) + acc[t][j];        // xj + emb
                mvs[t] = (unsigned short)bf16r(mv);
                float s = mv + b2f(xt[t]);
                float u0 = s + cbe0[t]; u0 = fmaxf(u0, NEG * u0);
                float u1 = s + cbe1[t]; u1 = fmaxf(u1, NEG * u1);
                q0 = fmaf(u0, attv[t], q0);
                q1 = fmaf(u1, attv[t], q1);
            }
            if (MODE >= 1)
                *reinterpret_cast<ushort8*>(msg + (size_t)(p0 + idx) * F + col * 8) = mvs;
#pragma unroll
            for (int off = 8; off; off >>= 1) {
                q0 += __shfl_xor(q0, off, 16);
                q1 += __shfl_xor(q1, off, 16);
            }
            if (col == 0) {
                float2 o; o.x = q0 * as0; o.y = q1 * as1;
                lgs2[p0 + idx] = o;
            }
        }
        // (f) rotate
        pe = pe_n; tgtv = tgt_n;
        pe_n = pe_nn; tgt_n = tgt_nn;
        rc0 = rn0; rc1 = rn1; rc2 = rn2; rc3 = rn3;
    }
}

// ---------------- streaming aggregation from packed msg (r19 known-good) ----------------
// lane reads packed q = {2*lane, 2*lane+1}; f = (q&7)*16 + (q>>3)
__global__ __launch_bounds__(512) void agg_msg(
    const int* __restrict__ offs, const int2* __restrict__ perm2,
    const unsigned short* __restrict__ msg, const float* __restrict__ ebias,
    const float* __restrict__ lgs,
    float* __restrict__ out, float* __restrict__ alpha_out) {
    int lane = threadIdx.x & 63;
    int node = blockIdx.x * 8 + (threadIdx.x >> 6);
    if (node >= NN) return;
    int beg = offs[node], end = offs[node + 1];
    int deg = end - beg;
    float* orow = out + (size_t)node * (C * F);
    float2* orow2 = reinterpret_cast<float2*>(orow);
    if (deg == 0) {
        float2 z; z.x = 0.f; z.y = 0.f;
        orow2[lane] = z; orow2[64 + lane] = z;
        return;
    }
    const float2* lgs2 = reinterpret_cast<const float2*>(lgs);
    float2* al2 = reinterpret_cast<float2*>(alpha_out);

    float m0 = -FLTMAX, m1 = -FLTMAX;
    for (int j = beg + lane; j < end; j += 64) {
        float2 lg = lgs2[j];
        m0 = fmaxf(m0, lg.x); m1 = fmaxf(m1, lg.y);
    }
#pragma unroll
    for (int off = 32; off; off >>= 1) {
        m0 = fmaxf(m0, __shfl_xor(m0, off, 64));
        m1 = fmaxf(m1, __shfl_xor(m1, off, 64));
    }
    float su0 = 0.f, su1 = 0.f;
    for (int j = beg + lane; j < end; j += 64) {
        float2 lg = lgs2[j];
        su0 += __expf(lg.x - m0); su1 += __expf(lg.y - m1);
    }
#pragma unroll
    for (int off = 32; off; off >>= 1) {
        su0 += __shfl_xor(su0, off, 64);
        su1 += __shfl_xor(su1, off, 64);
    }
    float inv0 = 1.f / (su0 + 1e-16f), inv1 = 1.f / (su1 + 1e-16f);

    float g00 = 0.f, g01 = 0.f, g10 = 0.f, g11 = 0.f;
    for (int cb0 = beg; cb0 < end; cb0 += 64) {
        int cnt = min(64, end - cb0);
        int jl = cb0 + min(lane, cnt - 1);
        bool act = lane < cnt;
        int el = perm2[jl].x;
        float2 lgl = lgs2[jl];
        float e0v = act ? __expf(lgl.x - m0) : 0.f;
        float e1v = act ? __expf(lgl.y - m1) : 0.f;
        if (act) { float2 av; av.x = e0v * inv0; av.y = e1v * inv1; al2[el] = av; }
#pragma unroll 4
        for (int i = 0; i < cnt; ++i) {
            float a0 = __shfl(e0v, i, 64) * inv0;
            float a1 = __shfl(e1v, i, 64) * inv1;
            unsigned mv = *reinterpret_cast<const unsigned*>(
                msg + (size_t)(cb0 + i) * F + lane * 2);
            float f0 = __uint_as_float((mv & 0xffffu) << 16);
            float f1 = __uint_as_float(mv & 0xffff0000u);
            g00 = fmaf(a0, f0, g00); g01 = fmaf(a0, f1, g01);
            g10 = fmaf(a1, f0, g10); g11 = fmaf(a1, f1, g11);
        }
    }
    float sa0 = su0 * inv0, sa1 = su1 * inv1;
    // packed positions q0=2*lane (t even), q1=2*lane+1 -> f = (q&7)*16 + (q>>3)
    int q0i = 2 * lane;
    int f0i = (q0i & 7) * 16 + (q0i >> 3);
    int f1i = f0i + 16;                      // q1 = q0+1, t+1
    orow[f0i]       = g00 + ebias[f0i * 2] * sa0;
    orow[f1i]       = g01 + ebias[f1i * 2] * sa0;
    orow[F + f0i]   = g10 + ebias[f0i * 2 + 1] * sa1;
    orow[F + f1i]   = g11 + ebias[f1i * 2 + 1] * sa1;
}

// ---------------- fallback (never expected to run): gather agg + H + emb_gemm ----------------
__device__ __forceinline__ float xbval(const unsigned short* __restrict__ xbp,
                                       int n, int f) {
    return b2f(xbp[(size_t)n * F + (f & 15) * 8 + (f >> 4)]);
}

__global__ __launch_bounds__(512) void agg_fast(
    const int* __restrict__ offs, const int2* __restrict__ perm2,
    const float* __restrict__ ea, const unsigned short* __restrict__ xbp,
    const float* __restrict__ ebias, const float* __restrict__ lgs,
    float* __restrict__ out, float* __restrict__ alpha_out,
    float* __restrict__ H) {
    int lane = threadIdx.x & 63;
    int node = blockIdx.x * 8 + (threadIdx.x >> 6);
    if (node >= NN) return;
    int beg = offs[node], end = offs[node + 1];
    int deg = end - beg;
    float* orow = out + (size_t)node * (C * F);
    float* hrow = H + (size_t)node * (C * ED);

    if (deg == 0) {
        orow[lane] = 0.f; orow[64 + lane] = 0.f;
        orow[128 + lane] = 0.f; orow[192 + lane] = 0.f;
        if (lane < 32) { hrow[lane * 4] = 0.f; hrow[lane * 4 + 1] = 0.f;
                         hrow[lane * 4 + 2] = 0.f; hrow[lane * 4 + 3] = 0.f; }
        return;
    }
    const float2* lgs2 = reinterpret_cast<const float2*>(lgs);
    float2* al2 = reinterpret_cast<float2*>(alpha_out);

    float m0 = -FLTMAX, m1 = -FLTMAX;
    for (int j = beg + lane; j < end; j += 64) {
        float2 lg = lgs2[j];
        m0 = fmaxf(m0, lg.x); m1 = fmaxf(m1, lg.y);
    }
#pragma unroll
    for (int off = 32; off; off >>= 1) {
        m0 = fmaxf(m0, __shfl_xor(m0, off, 64));
        m1 = fmaxf(m1, __shfl_xor(m1, off, 64));
    }
    float s0 = 0.f, s1 = 0.f;
    for (int j = beg + lane; j < end; j += 64) {
        float2 lg = lgs2[j];
        s0 += __expf(lg.x - m0); s1 += __expf(lg.y - m1);
    }
#pragma unroll
    for (int off = 32; off; off >>= 1) {
        s0 += __shfl_xor(s0, off, 64);
        s1 += __shfl_xor(s1, off, 64);
    }
    float inv0 = 1.f / (s0 + 1e-16f), inv1 = 1.f / (s1 + 1e-16f);

    float h0 = 0.f, h1 = 0.f;
    float g00 = 0.f, g01 = 0.f, g10 = 0.f, g11 = 0.f;
    for (int j = beg; j < end; ++j) {
        int2 pe; pe.x = __builtin_amdgcn_readfirstlane(perm2[j].x);
        pe.y = __builtin_amdgcn_readfirstlane(perm2[j].y);
        float2 lg = lgs2[j];
        float a0 = __builtin_amdgcn_readfirstlane(__expf(lg.x - m0)) * inv0;
        float a1 = __builtin_amdgcn_readfirstlane(__expf(lg.y - m1)) * inv1;
        if (lane == 0) { float2 av; av.x = a0; av.y = a1; al2[pe.x] = av; }
        float av = ea[(size_t)pe.x * ED + lane];
        h0 = fmaf(a0, av, h0); h1 = fmaf(a1, av, h1);
        float xv0 = xbval(xbp, pe.y, lane);
        float xv1 = xbval(xbp, pe.y, 64 + lane);
        g00 = fmaf(a0, xv0, g00); g01 = fmaf(a1, xv0, g01);
        g10 = fmaf(a0, xv1, g10); g11 = fmaf(a1, xv1, g11);
    }
    hrow[lane] = h0; hrow[64 + lane] = h1;
    float sa0 = s0 * inv0, sa1 = s1 * inv1;
    orow[lane]       = g00 + ebias[lane * 2] * sa0;
    orow[64 + lane]  = g10 + ebias[(64 + lane) * 2] * sa0;
    orow[128 + lane] = g01 + ebias[lane * 2 + 1] * sa1;
    orow[192 + lane] = g11 + ebias[(64 + lane) * 2 + 1] * sa1;
}

__global__ __launch_bounds__(512) void emb_gemm(const float* __restrict__ H,
                                                const float* __restrict__ W_e,
                                                float* __restrict__ out) {
    __shared__ float WeT[ED][F];
    for (int i = threadIdx.x; i < ED * F; i += 512) {
        int f = i & (F - 1), k = i >> 7;
        WeT[k][f] = W_e[(size_t)f * ED + k];
    }
    __syncthreads();
    int lane = threadIdx.x & 63, wid = threadIdx.x >> 6;
    const int R = NN * C;
    for (int row = blockIdx.x * 8 + wid; row < R; row += gridDim.x * 8) {
        float h = H[(size_t)row * ED + lane];
        float m0 = 0.f, m1 = 0.f;
#pragma unroll
        for (int k = 0; k < ED; ++k) {
            float hk = __shfl(h, k, 64);
            m0 = fmaf(hk, WeT[k][lane], m0);
            m1 = fmaf(hk, WeT[k][lane + 64], m1);
        }
        float* op = out + (size_t)row * F;
        op[lane] += m0;
        op[lane + 64] += m1;
    }
}

extern "C" void kernel_launch(void* const* d_in, const int* in_sizes, int n_in,
                              void* d_out, int out_size, void* d_ws, size_t ws_size,
                              hipStream_t stream) {
    const float* x      = (const float*)d_in[0];
    const int*   ei     = (const int*)d_in[1];
    const float* ea     = (const float*)d_in[2];
    const float* W_l    = (const float*)d_in[3];
    const float* cb     = (const float*)d_in[4];
    const float* att    = (const float*)d_in[5];
    const float* att_sc = (const float*)d_in[6];
    const float* W_e    = (const float*)d_in[7];
    const float* ebias  = (const float*)d_in[8];

    float* out = (float*)d_out;
    float* alpha_out = out + (size_t)NN * C * F;

    float* ws = (float*)d_ws;
    unsigned short* xbp = (unsigned short*)ws;   // 12.8 MB (region reserves 25.6)
    float* lgs  = ws + 6400000;                  // 4 MB
    int* ibase  = (int*)(ws + 7400000);
    int* counts = ibase;                         // NN (becomes cursor)
    int* offs   = ibase + NN;                    // NN+1 (pad to 100064)
    int* bsum   = ibase + 100064;                // 64
    int* tgts   = ibase + 100128;                // NE
    int2* perm2 = (int2*)(ibase + 100128 + NE);  // NE int2
    char* tail = (char*)(ibase + 100128 + 3 * NE);
    tail = (char*)(((size_t)tail + 15) & ~(size_t)15);
    size_t head_bytes = (size_t)(tail - (char*)d_ws);
    size_t msg_bytes = (size_t)NE * F * 2;       // 128 MB
    bool use_msg = ws_size >= head_bytes + msg_bytes + 64;
    unsigned short* msg = (unsigned short*)tail;
    float* H = (float*)tail;

    hipMemsetAsync(counts, 0, NN * sizeof(int), stream);

    proj_hist<<<PROJ_BLOCKS + HIST_BLOCKS, 256, 0, stream>>>(x, W_l, xbp, ei, counts);

    const int NB = (NN + 1023) / 1024; // 49
    scan1_kernel<<<NB, 1024, 0, stream>>>(counts, offs, bsum);
    scan3b_kernel<<<NB, 1024, 0, stream>>>(offs, bsum, counts); // counts = cursor
    scatter_kernel<<<(NE + 255) / 256, 256, 0, stream>>>(ei, counts, perm2, tgts);

    if (use_msg) {
        edge_logits_mfma<1><<<2048, 256, 0, stream>>>(perm2, tgts, ea, xbp, W_e,
                                                      cb, att, att_sc, ebias,
                                                      lgs, msg);
        agg_msg<<<(NN + 7) / 8, 512, 0, stream>>>(offs, perm2, msg, ebias, lgs,
                                                  out, alpha_out);
    } else {
        edge_logits_mfma<0><<<2048, 256, 0, stream>>>(perm2, tgts, ea, xbp, W_e,
                                                      cb, att, att_sc, ebias,
                                                      lgs, (unsigned short*)0);
        agg_fast<<<(NN + 7) / 8, 512, 0, stream>>>(offs, perm2, ea, xbp, ebias, lgs,
                                                   out, alpha_out, H);
        emb_gemm<<<1024, 512, 0, stream>>>(H, W_e, out);
    }
}